// Round 1
// baseline (1347.163 us; speedup 1.0000x reference)
//
#include <hip/hip_runtime.h>

// ---------------------------------------------------------------------------
// 2-layer bipartite GAT (PyG GATConv semantics), MI355X / gfx950.
// Round 1: correct fp32 baseline.
//   - dst-side projections folded: a_dst = x @ (W_dst @ att_dst)  [exact]
//   - segment softmax via 3 edge passes with atomics (ordered-uint atomicMax)
//   - message aggregation via per-edge-block atomicAdd scatter
// ---------------------------------------------------------------------------

constexpr int N1 = 262144, N2 = 65536, N3 = 16384;
constexpr int E1 = 524288, E2 = 262144;
constexpr int IN_DIM = 128, HID = 64, HEADS = 4, OUT_DIM = 64;
constexpr int HD = HEADS * HID;   // 256
constexpr float NEG_SLOPE = 0.2f;
constexpr float BN_EPS = 1e-5f;
constexpr unsigned ORD_NEG_INF = 0x007FFFFFu;  // f2ord(-inf)

__device__ inline unsigned f2ord(float f) {
  unsigned u = __float_as_uint(f);
  return (u & 0x80000000u) ? ~u : (u | 0x80000000u);
}
__device__ inline float ord2f(unsigned u) {
  return (u & 0x80000000u) ? __uint_as_float(u & 0x7FFFFFFFu) : __uint_as_float(~u);
}
__device__ inline float wave_sum(float v) {
#pragma unroll
  for (int off = 32; off > 0; off >>= 1) v += __shfl_xor(v, off, 64);
  return v;
}

// --- fold att into W for the a-score projections: wa[h][k] = sum_c W[k,h*C+c]*att[h,c]
__global__ __launch_bounds__(256) void precompute_wa(
    const float* __restrict__ W1s, const float* __restrict__ W1d,
    const float* __restrict__ A1s, const float* __restrict__ A1d,
    const float* __restrict__ W2s, const float* __restrict__ W2d,
    const float* __restrict__ A2s, const float* __restrict__ A2d,
    float* __restrict__ wa1s, float* __restrict__ wa1d,
    float* __restrict__ wa2s, float* __restrict__ wa2d) {
  int t = blockIdx.x * 256 + threadIdx.x;
  if (t < HEADS * IN_DIM) {           // layout [h][k]
    int h = t >> 7, k = t & 127;
    float s = 0.f, d = 0.f;
    for (int c = 0; c < HID; ++c) {
      s += W1s[k * HD + h * HID + c] * A1s[h * HID + c];
      d += W1d[k * HD + h * HID + c] * A1d[h * HID + c];
    }
    wa1s[t] = s; wa1d[t] = d;
  } else if (t < HEADS * IN_DIM + HD) {
    int k = t - HEADS * IN_DIM;
    float s = 0.f, d = 0.f;
    for (int c = 0; c < OUT_DIM; ++c) {
      s += W2s[k * OUT_DIM + c] * A2s[c];
      d += W2d[k * OUT_DIM + c] * A2d[c];
    }
    wa2s[k] = s; wa2d[k] = d;
  }
}

// --- zero/init all accumulated buffers (ws is poisoned 0xAA before each launch)
__global__ void init_ws_kernel(unsigned* __restrict__ emax1, float* __restrict__ den1,
                               float* __restrict__ acc1, unsigned* __restrict__ emax2,
                               float* __restrict__ den2, float* __restrict__ acc2) {
  int i = blockIdx.x * blockDim.x + threadIdx.x;
  int stride = gridDim.x * blockDim.x;
  for (int j = i; j < N2 * HEADS; j += stride) { emax1[j] = ORD_NEG_INF; den1[j] = 0.f; }
  for (int j = i; j < N2 * HD; j += stride) acc1[j] = 0.f;
  for (int j = i; j < N3; j += stride) { emax2[j] = ORD_NEG_INF; den2[j] = 0.f; }
  for (int j = i; j < N3 * OUT_DIM; j += stride) acc2[j] = 0.f;
}

// --- fp32 tiled GEMM: C[M,N] = A[M,K] * B[K,N], all row-major, dims divide tiles
template <int BM, int BN, int BK, int TM, int TN>
__global__ __launch_bounds__(256) void sgemm(const float* __restrict__ A,
                                             const float* __restrict__ B,
                                             float* __restrict__ C, int M, int N, int K) {
  constexpr int PAD = 4;
  __shared__ float As[BK][BM + PAD];   // transposed A tile
  __shared__ float Bs[BK][BN + PAD];
  const int tid = threadIdx.x;
  constexpr int TCOLS = BN / TN;       // 16
  const int tcol = tid % TCOLS;
  const int trow = tid / TCOLS;
  const int row0 = blockIdx.y * BM;
  const int col0 = blockIdx.x * BN;

  float acc[TM][TN];
#pragma unroll
  for (int i = 0; i < TM; ++i)
#pragma unroll
    for (int j = 0; j < TN; ++j) acc[i][j] = 0.f;

  for (int k0 = 0; k0 < K; k0 += BK) {
    __syncthreads();
    constexpr int AV = BM * BK / 4;
#pragma unroll
    for (int idx = tid; idx < AV; idx += 256) {
      int m = idx / (BK / 4);
      int kq = idx % (BK / 4);
      const float4 v = *reinterpret_cast<const float4*>(&A[(size_t)(row0 + m) * K + k0 + kq * 4]);
      As[kq * 4 + 0][m] = v.x; As[kq * 4 + 1][m] = v.y;
      As[kq * 4 + 2][m] = v.z; As[kq * 4 + 3][m] = v.w;
    }
    constexpr int BV = BK * BN / 4;
#pragma unroll
    for (int idx = tid; idx < BV; idx += 256) {
      int k = idx / (BN / 4);
      int nq = idx % (BN / 4);
      const float4 v = *reinterpret_cast<const float4*>(&B[(size_t)(k0 + k) * N + col0 + nq * 4]);
      *reinterpret_cast<float4*>(&Bs[k][nq * 4]) = v;
    }
    __syncthreads();
#pragma unroll
    for (int kk = 0; kk < BK; ++kk) {
      float a[TM], b[TN];
#pragma unroll
      for (int i = 0; i < TM; i += 4)
        *reinterpret_cast<float4*>(&a[i]) = *reinterpret_cast<const float4*>(&As[kk][trow * TM + i]);
#pragma unroll
      for (int j = 0; j < TN; j += 4)
        *reinterpret_cast<float4*>(&b[j]) = *reinterpret_cast<const float4*>(&Bs[kk][tcol * TN + j]);
#pragma unroll
      for (int i = 0; i < TM; ++i)
#pragma unroll
        for (int j = 0; j < TN; ++j) acc[i][j] = fmaf(a[i], b[j], acc[i][j]);
    }
  }
#pragma unroll
  for (int i = 0; i < TM; ++i)
#pragma unroll
    for (int j = 0; j < TN; j += 4) {
      float4 v = {acc[i][j], acc[i][j + 1], acc[i][j + 2], acc[i][j + 3]};
      *reinterpret_cast<float4*>(&C[(size_t)(row0 + trow * TM + i) * N + col0 + tcol * TN + j]) = v;
    }
}

// --- layer-1 attention scores: a[i][h] = x[i,:] . wa[h][:]; one wave per row
__global__ __launch_bounds__(256) void att_scores1(
    const float* __restrict__ x, const float* __restrict__ wa_s,
    const float* __restrict__ wa_d, float* __restrict__ a_src, float* __restrict__ a_dst) {
  __shared__ float ws[HEADS * IN_DIM], wd[HEADS * IN_DIM];
  for (int i = threadIdx.x; i < HEADS * IN_DIM; i += 256) { ws[i] = wa_s[i]; wd[i] = wa_d[i]; }
  __syncthreads();
  int lane = threadIdx.x & 63;
  int row = blockIdx.x * 4 + (threadIdx.x >> 6);
  float x0 = x[(size_t)row * IN_DIM + lane];
  float x1 = x[(size_t)row * IN_DIM + 64 + lane];
#pragma unroll
  for (int h = 0; h < HEADS; ++h) {
    float p = fmaf(x0, ws[h * IN_DIM + lane], x1 * ws[h * IN_DIM + 64 + lane]);
    p = wave_sum(p);
    if (lane == 0) a_src[row * HEADS + h] = p;
  }
  if (row < N2) {
#pragma unroll
    for (int h = 0; h < HEADS; ++h) {
      float p = fmaf(x0, wd[h * IN_DIM + lane], x1 * wd[h * IN_DIM + 64 + lane]);
      p = wave_sum(p);
      if (lane == 0) a_dst[row * HEADS + h] = p;
    }
  }
}

// --- layer-2 attention scores (heads=1, K=HD)
__global__ __launch_bounds__(256) void att_scores2(
    const float* __restrict__ h, const float* __restrict__ wa_s,
    const float* __restrict__ wa_d, float* __restrict__ a_src, float* __restrict__ a_dst) {
  __shared__ float ws[HD], wd[HD];
  for (int i = threadIdx.x; i < HD; i += 256) { ws[i] = wa_s[i]; wd[i] = wa_d[i]; }
  __syncthreads();
  int lane = threadIdx.x & 63;
  int row = blockIdx.x * 4 + (threadIdx.x >> 6);
  const float* hr = h + (size_t)row * HD;
  float p = 0.f, q = 0.f;
#pragma unroll
  for (int c0 = 0; c0 < HD; c0 += 64) {
    float v = hr[c0 + lane];
    p = fmaf(v, ws[c0 + lane], p);
    q = fmaf(v, wd[c0 + lane], q);
  }
  p = wave_sum(p);
  if (lane == 0) a_src[row] = p;
  if (row < N3) {
    q = wave_sum(q);
    if (lane == 0) a_dst[row] = q;
  }
}

// --- edge pass 1: e = leaky_relu(a_src[src]+a_dst[dst]); store e; atomicMax per segment
template <int H>
__global__ __launch_bounds__(256) void edge_max(
    const int* __restrict__ src, const int* __restrict__ dst,
    const float* __restrict__ a_src, const float* __restrict__ a_dst,
    float* __restrict__ e_out, unsigned* __restrict__ emax, int E) {
  int i = blockIdx.x * 256 + threadIdx.x;
  if (i >= E) return;
  int s = src[i], d = dst[i];
#pragma unroll
  for (int h = 0; h < H; ++h) {
    float e = a_src[s * H + h] + a_dst[d * H + h];
    e = e > 0.f ? e : NEG_SLOPE * e;
    e_out[i * H + h] = e;
    atomicMax(&emax[d * H + h], f2ord(e));
  }
}

// --- edge pass 2: p = exp(e - emax[dst]); store p in-place; atomicAdd denom
template <int H>
__global__ __launch_bounds__(256) void edge_expsum(
    const int* __restrict__ dst, float* __restrict__ e_p,
    const unsigned* __restrict__ emax, float* __restrict__ denom, int E) {
  int i = blockIdx.x * 256 + threadIdx.x;
  if (i >= E) return;
  int d = dst[i];
#pragma unroll
  for (int h = 0; h < H; ++h) {
    float m = ord2f(emax[d * H + h]);
    float p = expf(e_p[i * H + h] - m);
    e_p[i * H + h] = p;
    atomicAdd(&denom[d * H + h], p);
  }
}

// --- edge pass 3 (layer 1): block per edge, thread t = channel (h = t>>6)
__global__ __launch_bounds__(256) void edge_scatter1(
    const int* __restrict__ src, const int* __restrict__ dst,
    const float* __restrict__ p, const float* __restrict__ denom,
    const float* __restrict__ hsrc, float* __restrict__ acc) {
  int e = blockIdx.x;
  int t = threadIdx.x;
  int h = t >> 6;
  int s = src[e], d = dst[e];
  float alpha = p[e * HEADS + h] / fmaxf(denom[d * HEADS + h], 1e-16f);
  atomicAdd(&acc[(size_t)d * HD + t], alpha * hsrc[(size_t)s * HD + t]);
}

// --- edge pass 3 (layer 2): wave per edge, lane = channel
__global__ __launch_bounds__(256) void edge_scatter2(
    const int* __restrict__ src, const int* __restrict__ dst,
    const float* __restrict__ p, const float* __restrict__ denom,
    const float* __restrict__ hsrc, float* __restrict__ acc) {
  int e = blockIdx.x * 4 + (threadIdx.x >> 6);
  int l = threadIdx.x & 63;
  int s = src[e], d = dst[e];
  float alpha = p[e] / fmaxf(denom[d], 1e-16f);
  atomicAdd(&acc[d * OUT_DIM + l], alpha * hsrc[(size_t)s * OUT_DIM + l]);
}

// --- bias + BatchNorm(eval) + ELU, in place on acc1
__global__ __launch_bounds__(256) void bn_elu(
    float* __restrict__ h, const float* __restrict__ bias,
    const float* __restrict__ gamma, const float* __restrict__ beta,
    const float* __restrict__ mean, const float* __restrict__ var) {
  int j = blockIdx.x * 256 + threadIdx.x;
  int c = j & (HD - 1);
  float v = h[j] + bias[c];
  v = (v - mean[c]) * gamma[c] * rsqrtf(var[c] + BN_EPS) + beta[c];
  h[j] = v > 0.f ? v : expm1f(v);
}

// --- final: out = acc2 + b2
__global__ __launch_bounds__(256) void add_bias_out(
    const float* __restrict__ acc, const float* __restrict__ b, float* __restrict__ out) {
  int j = blockIdx.x * 256 + threadIdx.x;
  out[j] = acc[j] + b[j & (OUT_DIM - 1)];
}

extern "C" void kernel_launch(void* const* d_in, const int* in_sizes, int n_in,
                              void* d_out, int out_size, void* d_ws, size_t ws_size,
                              hipStream_t stream) {
  const float* x     = (const float*)d_in[0];
  const float* W1s   = (const float*)d_in[1];
  const float* W1d   = (const float*)d_in[2];
  const float* A1s   = (const float*)d_in[3];
  const float* A1d   = (const float*)d_in[4];
  const float* b1    = (const float*)d_in[5];
  const float* gamma = (const float*)d_in[6];
  const float* beta  = (const float*)d_in[7];
  const float* rmean = (const float*)d_in[8];
  const float* rvar  = (const float*)d_in[9];
  const float* W2s   = (const float*)d_in[10];
  const float* W2d   = (const float*)d_in[11];
  const float* A2s   = (const float*)d_in[12];
  const float* A2d   = (const float*)d_in[13];
  const float* b2    = (const float*)d_in[14];
  const int* src1    = (const int*)d_in[15];
  const int* dst1    = (const int*)d_in[16];
  const int* src2    = (const int*)d_in[17];
  const int* dst2    = (const int*)d_in[18];

  float* w = (float*)d_ws;
  size_t off = 0;
  auto alloc = [&](size_t n) { float* p = w + off; off += n; return p; };
  float* h1       = alloc((size_t)N1 * HD);        // 268 MB: x @ W1_src
  float* a1s      = alloc((size_t)N1 * HEADS);
  float* a1d      = alloc((size_t)N2 * HEADS);
  float* e1       = alloc((size_t)E1 * HEADS);     // e -> p in place
  unsigned* emax1 = (unsigned*)alloc((size_t)N2 * HEADS);
  float* den1     = alloc((size_t)N2 * HEADS);
  float* acc1     = alloc((size_t)N2 * HD);        // layer-1 out -> h (post BN/ELU)
  float* h2       = alloc((size_t)N2 * OUT_DIM);   // h @ W2_src
  float* a2s      = alloc((size_t)N2);
  float* a2d      = alloc((size_t)N3);
  float* e2       = alloc((size_t)E2);
  unsigned* emax2 = (unsigned*)alloc((size_t)N3);
  float* den2     = alloc((size_t)N3);
  float* acc2     = alloc((size_t)N3 * OUT_DIM);
  float* wa1s     = alloc(HEADS * IN_DIM);
  float* wa1d     = alloc(HEADS * IN_DIM);
  float* wa2s     = alloc(HD);
  float* wa2d     = alloc(HD);
  (void)ws_size; (void)in_sizes; (void)n_in; (void)out_size;

  precompute_wa<<<3, 256, 0, stream>>>(W1s, W1d, A1s, A1d, W2s, W2d, A2s, A2d,
                                       wa1s, wa1d, wa2s, wa2d);
  init_ws_kernel<<<4096, 256, 0, stream>>>(emax1, den1, acc1, emax2, den2, acc2);

  // ---- layer 1 ----
  sgemm<128, 128, 16, 8, 8><<<dim3(HD / 128, N1 / 128), 256, 0, stream>>>(
      x, W1s, h1, N1, HD, IN_DIM);
  att_scores1<<<N1 / 4, 256, 0, stream>>>(x, wa1s, wa1d, a1s, a1d);
  edge_max<HEADS><<<E1 / 256, 256, 0, stream>>>(src1, dst1, a1s, a1d, e1, emax1, E1);
  edge_expsum<HEADS><<<E1 / 256, 256, 0, stream>>>(dst1, e1, emax1, den1, E1);
  edge_scatter1<<<E1, 256, 0, stream>>>(src1, dst1, e1, den1, h1, acc1);
  bn_elu<<<(N2 * HD) / 256, 256, 0, stream>>>(acc1, b1, gamma, beta, rmean, rvar);

  // ---- layer 2 ----
  sgemm<128, 64, 16, 8, 4><<<dim3(OUT_DIM / 64, N2 / 128), 256, 0, stream>>>(
      acc1, W2s, h2, N2, OUT_DIM, HD);
  att_scores2<<<N2 / 4, 256, 0, stream>>>(acc1, wa2s, wa2d, a2s, a2d);
  edge_max<1><<<E2 / 256, 256, 0, stream>>>(src2, dst2, a2s, a2d, e2, emax2, E2);
  edge_expsum<1><<<E2 / 256, 256, 0, stream>>>(dst2, e2, emax2, den2, E2);
  edge_scatter2<<<E2 / 4, 256, 0, stream>>>(src2, dst2, e2, den2, h2, acc2);
  add_bias_out<<<(N3 * OUT_DIM) / 256, 256, 0, stream>>>(acc2, b2, (float*)d_out);
}

// Round 2
// 600.642 us; speedup vs baseline: 2.2429x; 2.2429x over previous
//
#include <hip/hip_runtime.h>

// ---------------------------------------------------------------------------
// 2-layer bipartite GAT, MI355X / gfx950. Round 2:
//  - CSR built on device (hist + scan + scatter); per-dst online-softmax
//    aggregation (no output atomics), fused with bias/BN/ELU epilogues.
//  - Layer-1 GEMM in bf16 MFMA (16x16x32), single K=128 LDS-resident tile,
//    global_load_lds staging, XOR-swizzled rows (swizzle applied at the
//    fp32->bf16 conversion, LDS copy stays linear).
//  - h1 stored bf16 (134 MB -> L3-resident for the edge gather).
// ---------------------------------------------------------------------------

constexpr int N1 = 262144, N2 = 65536, N3 = 16384;
constexpr int E1 = 524288, E2 = 262144;
constexpr int IN_DIM = 128, HID = 64, HEADS = 4, OUT_DIM = 64;
constexpr int HD = HEADS * HID;   // 256
constexpr float NEG_SLOPE = 0.2f;
constexpr float BN_EPS = 1e-5f;

typedef __attribute__((ext_vector_type(8))) short bf16x8;
typedef __attribute__((ext_vector_type(8))) unsigned short ushort8;
typedef __attribute__((ext_vector_type(4))) float f32x4;

#define GLOAD_LDS16(gp, lp)                                              \
  __builtin_amdgcn_global_load_lds(                                      \
      (const __attribute__((address_space(1))) unsigned int*)(gp),       \
      (__attribute__((address_space(3))) unsigned int*)(lp), 16, 0, 0)

__device__ inline unsigned short f2bf(float f) {   // RNE
  unsigned u = __float_as_uint(f);
  u += 0x7FFFu + ((u >> 16) & 1u);
  return (unsigned short)(u >> 16);
}
__device__ inline float bf2f(unsigned short s) {
  return __uint_as_float(((unsigned)s) << 16);
}

// --- fold att into W: wa[h][k] = sum_c W[k, h*C+c] * att[h, c]
__global__ __launch_bounds__(256) void precompute_wa(
    const float* __restrict__ W1s, const float* __restrict__ W1d,
    const float* __restrict__ A1s, const float* __restrict__ A1d,
    const float* __restrict__ W2s, const float* __restrict__ W2d,
    const float* __restrict__ A2s, const float* __restrict__ A2d,
    float* __restrict__ wa1s, float* __restrict__ wa1d,
    float* __restrict__ wa2s, float* __restrict__ wa2d) {
  int t = blockIdx.x * 256 + threadIdx.x;
  if (t < HEADS * IN_DIM) {           // layout [h][k]
    int h = t >> 7, k = t & 127;
    float s = 0.f, d = 0.f;
    for (int c = 0; c < HID; ++c) {
      s += W1s[k * HD + h * HID + c] * A1s[h * HID + c];
      d += W1d[k * HD + h * HID + c] * A1d[h * HID + c];
    }
    wa1s[t] = s; wa1d[t] = d;
  } else if (t < HEADS * IN_DIM + HD) {
    int k = t - HEADS * IN_DIM;
    float s = 0.f, d = 0.f;
    for (int c = 0; c < OUT_DIM; ++c) {
      s += W2s[k * OUT_DIM + c] * A2s[c];
      d += W2d[k * OUT_DIM + c] * A2d[c];
    }
    wa2s[k] = s; wa2d[k] = d;
  }
}

__global__ void init_k(int* __restrict__ deg1, int* __restrict__ deg2,
                       int* __restrict__ rp1, int* __restrict__ rp2) {
  int i = blockIdx.x * 256 + threadIdx.x;
  int stride = gridDim.x * 256;
  for (int j = i; j < N2; j += stride) deg1[j] = 0;
  for (int j = i; j < N3; j += stride) deg2[j] = 0;
  if (i == 0) { rp1[0] = 0; rp2[0] = 0; }
}

// --- CSR build ---
__global__ __launch_bounds__(256) void hist_k(const int* __restrict__ dst,
                                              int* __restrict__ deg,
                                              int* __restrict__ rank, int E) {
  int i = blockIdx.x * 256 + threadIdx.x;
  if (i < E) rank[i] = atomicAdd(&deg[dst[i]], 1);
}

__global__ __launch_bounds__(256) void scan1_k(const int* __restrict__ in,
                                               int* __restrict__ out,
                                               int* __restrict__ bsums, int n) {
  __shared__ int s[256];
  int b = blockIdx.x, tid = threadIdx.x;
  int i0 = b * 1024 + tid * 4;
  int x0 = (i0 < n) ? in[i0] : 0;
  int x1 = (i0 + 1 < n) ? in[i0 + 1] : 0;
  int x2 = (i0 + 2 < n) ? in[i0 + 2] : 0;
  int x3 = (i0 + 3 < n) ? in[i0 + 3] : 0;
  int t = x0 + x1 + x2 + x3;
  s[tid] = t;
  __syncthreads();
  for (int off = 1; off < 256; off <<= 1) {
    int v = (tid >= off) ? s[tid - off] : 0;
    __syncthreads();
    s[tid] += v;
    __syncthreads();
  }
  int base = s[tid] - t;
  if (i0 < n) out[i0] = base + x0;
  if (i0 + 1 < n) out[i0 + 1] = base + x0 + x1;
  if (i0 + 2 < n) out[i0 + 2] = base + x0 + x1 + x2;
  if (i0 + 3 < n) out[i0 + 3] = base + t;
  if (tid == 255) bsums[b] = s[255];
}

__global__ void scan2_k(int* __restrict__ bs, int nb) {
  __shared__ int s[256];
  int tid = threadIdx.x;
  s[tid] = (tid < nb) ? bs[tid] : 0;
  __syncthreads();
  for (int off = 1; off < 256; off <<= 1) {
    int v = (tid >= off) ? s[tid - off] : 0;
    __syncthreads();
    s[tid] += v;
    __syncthreads();
  }
  if (tid < nb) bs[tid] = s[tid];
}

__global__ __launch_bounds__(256) void scan3_k(int* __restrict__ out,
                                               const int* __restrict__ bs, int n) {
  int b = blockIdx.x;
  if (b == 0) return;
  int add = bs[b - 1];
  int i0 = b * 1024 + threadIdx.x * 4;
  if (i0 < n) out[i0] += add;
  if (i0 + 1 < n) out[i0 + 1] += add;
  if (i0 + 2 < n) out[i0 + 2] += add;
  if (i0 + 3 < n) out[i0 + 3] += add;
}

__global__ __launch_bounds__(256) void scatter_k(const int* __restrict__ src,
                                                 const int* __restrict__ dst,
                                                 const int* __restrict__ rp,
                                                 const int* __restrict__ rank,
                                                 int* __restrict__ srcs, int E) {
  int i = blockIdx.x * 256 + threadIdx.x;
  if (i < E) srcs[rp[dst[i]] + rank[i]] = src[i];
}

// --- fused: x -> bf16 (row-swizzled) + layer-1 attention scores
//     block = 16 rows x 16 groups of 8 elems
__global__ __launch_bounds__(256) void conv_scores1(
    const float* __restrict__ x, const float* __restrict__ wa_s,
    const float* __restrict__ wa_d, unsigned short* __restrict__ xbf,
    float* __restrict__ a_src, float* __restrict__ a_dst) {
  __shared__ float ws[HEADS * IN_DIM], wd[HEADS * IN_DIM];
  int tid = threadIdx.x;
  for (int i = tid; i < HEADS * IN_DIM; i += 256) { ws[i] = wa_s[i]; wd[i] = wa_d[i]; }
  __syncthreads();
  int row = blockIdx.x * 16 + (tid >> 4);
  int g = tid & 15;
  float4 v0 = *reinterpret_cast<const float4*>(x + (size_t)row * IN_DIM + g * 8);
  float4 v1 = *reinterpret_cast<const float4*>(x + (size_t)row * IN_DIM + g * 8 + 4);
  float xv[8] = {v0.x, v0.y, v0.z, v0.w, v1.x, v1.y, v1.z, v1.w};
  ushort8 o;
#pragma unroll
  for (int j = 0; j < 8; ++j) o[j] = f2bf(xv[j]);
  *reinterpret_cast<ushort8*>(xbf + (size_t)row * IN_DIM + (size_t)(g ^ (row & 7)) * 8) = o;
#pragma unroll
  for (int h = 0; h < HEADS; ++h) {
    float p = 0.f;
#pragma unroll
    for (int j = 0; j < 8; ++j) p = fmaf(xv[j], ws[h * IN_DIM + g * 8 + j], p);
#pragma unroll
    for (int off = 1; off < 16; off <<= 1) p += __shfl_xor(p, off, 64);
    if (g == 0) a_src[(size_t)row * HEADS + h] = p;
  }
  if (row < N2) {
#pragma unroll
    for (int h = 0; h < HEADS; ++h) {
      float p = 0.f;
#pragma unroll
      for (int j = 0; j < 8; ++j) p = fmaf(xv[j], wd[h * IN_DIM + g * 8 + j], p);
#pragma unroll
      for (int off = 1; off < 16; off <<= 1) p += __shfl_xor(p, off, 64);
      if (g == 0) a_dst[(size_t)row * HEADS + h] = p;
    }
  }
}

// --- W1_src -> bf16, transposed [N=256][K=128], row-swizzled
__global__ __launch_bounds__(256) void conv_w1T(const float* __restrict__ W,
                                                unsigned short* __restrict__ WT) {
  int t = blockIdx.x * 256 + threadIdx.x;   // t in [0, 256*16)
  int n = t >> 4, g = t & 15;
  ushort8 o;
#pragma unroll
  for (int j = 0; j < 8; ++j) o[j] = f2bf(W[(size_t)(g * 8 + j) * HD + n]);
  *reinterpret_cast<ushort8*>(WT + (size_t)n * IN_DIM + (size_t)(g ^ (n & 7)) * 8) = o;
}

// --- bf16 MFMA GEMM: h1[N1][256] = x_bf16[N1][128] @ W1sT_bf16^T
//     single K=128 tile, 128x128 block, 4 waves (2x2), 64KB dynamic LDS
__global__ __launch_bounds__(256) void gemm1_bf16(
    const unsigned short* __restrict__ Abf, const unsigned short* __restrict__ Bbf,
    unsigned short* __restrict__ Cbf) {
  extern __shared__ char smem[];
  const int tid = threadIdx.x;
  const int wave = tid >> 6, lane = tid & 63;
  const int r0 = blockIdx.y * 128;
  const int c0 = blockIdx.x * 128;
  const char* gA = (const char*)(Abf + (size_t)r0 * IN_DIM);
  const char* gB = (const char*)(Bbf + (size_t)c0 * IN_DIM);
#pragma unroll
  for (int it = 0; it < 8; ++it) {
    int off = it * 4096 + wave * 1024;
    GLOAD_LDS16(gA + off + lane * 16, smem + off);
  }
#pragma unroll
  for (int it = 0; it < 8; ++it) {
    int off = it * 4096 + wave * 1024;
    GLOAD_LDS16(gB + off + lane * 16, smem + 32768 + off);
  }
  __syncthreads();

  const int wr = wave >> 1, wc = wave & 1;
  const int rbase = wr * 64, cbase = wc * 64;
  const int kl = (lane >> 4) * 8;
  const int fr = lane & 15;
  f32x4 acc[4][4] = {};
#pragma unroll
  for (int ks = 0; ks < 4; ++ks) {
    int k0 = ks * 32 + kl;
    bf16x8 a[4], b[4];
#pragma unroll
    for (int f = 0; f < 4; ++f) {
      int ra = rbase + f * 16 + fr;
      a[f] = *reinterpret_cast<const bf16x8*>(
          smem + ((size_t)ra * 128 + (k0 ^ ((ra & 7) << 3))) * 2);
      int cb = cbase + f * 16 + fr;
      b[f] = *reinterpret_cast<const bf16x8*>(
          smem + 32768 + ((size_t)cb * 128 + (k0 ^ ((cb & 7) << 3))) * 2);
    }
#pragma unroll
    for (int i = 0; i < 4; ++i)
#pragma unroll
      for (int j = 0; j < 4; ++j)
        acc[i][j] = __builtin_amdgcn_mfma_f32_16x16x32_bf16(a[i], b[j], acc[i][j], 0, 0, 0);
  }
#pragma unroll
  for (int i = 0; i < 4; ++i) {
    int row = r0 + rbase + i * 16 + (lane >> 4) * 4;
#pragma unroll
    for (int j = 0; j < 4; ++j) {
      int col = c0 + cbase + j * 16 + fr;
#pragma unroll
      for (int q = 0; q < 4; ++q)
        Cbf[(size_t)(row + q) * HD + col] = f2bf(acc[i][j][q]);
    }
  }
}

// --- layer-1 aggregation: block per dst node, wave = head, online softmax,
//     fused bias + BN(eval) + ELU
__global__ __launch_bounds__(256) void agg1(
    const int* __restrict__ rp, const int* __restrict__ srcs,
    const float* __restrict__ a_src, const float* __restrict__ a_dst,
    const unsigned short* __restrict__ h1, const float* __restrict__ b1,
    const float* __restrict__ gamma, const float* __restrict__ beta,
    const float* __restrict__ mean, const float* __restrict__ var,
    float* __restrict__ out) {
  int d = blockIdx.x;
  int wave = threadIdx.x >> 6, lane = threadIdx.x & 63;
  int beg = rp[d], end = rp[d + 1];
  float ad = a_dst[(size_t)d * HEADS + wave];
  float m = -__builtin_inff(), ssum = 0.f, acc = 0.f;
  for (int base = beg; base < end; base += 64) {
    int cnt = end - base; if (cnt > 64) cnt = 64;
    int sidx = 0; float e = -__builtin_inff();
    if (lane < cnt) {
      sidx = srcs[base + lane];
      float t = a_src[(size_t)sidx * HEADS + wave] + ad;
      e = t > 0.f ? t : NEG_SLOPE * t;
    }
    float cm = e;
#pragma unroll
    for (int off = 32; off; off >>= 1) cm = fmaxf(cm, __shfl_xor(cm, off, 64));
    float nm = fmaxf(m, cm);
    float p = (lane < cnt) ? __expf(e - nm) : 0.f;
    float ps = p;
#pragma unroll
    for (int off = 32; off; off >>= 1) ps += __shfl_xor(ps, off, 64);
    float scale = __expf(m - nm);   // first chunk: exp(-inf)=0, acc/ssum are 0
    acc *= scale;
    ssum = ssum * scale + ps;
    m = nm;
    for (int j = 0; j < cnt; ++j) {
      float pj = __shfl(p, j, 64);
      int sj = __shfl(sidx, j, 64);
      float hv = bf2f(h1[(size_t)sj * HD + wave * 64 + lane]);
      acc = fmaf(pj, hv, acc);
    }
  }
  int c = wave * 64 + lane;
  float v = acc / fmaxf(ssum, 1e-16f) + b1[c];
  v = (v - mean[c]) * gamma[c] * rsqrtf(var[c] + BN_EPS) + beta[c];
  out[(size_t)d * HD + c] = v > 0.f ? v : expm1f(v);
}

// --- fp32 tiled GEMM (layer 2): C[M,N] = A[M,K] * B[K,N]
template <int BM, int BN, int BK, int TM, int TN>
__global__ __launch_bounds__(256) void sgemm(const float* __restrict__ A,
                                             const float* __restrict__ B,
                                             float* __restrict__ C, int M, int N, int K) {
  constexpr int PAD = 4;
  __shared__ float As[BK][BM + PAD];
  __shared__ float Bs[BK][BN + PAD];
  const int tid = threadIdx.x;
  constexpr int TCOLS = BN / TN;
  const int tcol = tid % TCOLS;
  const int trow = tid / TCOLS;
  const int row0 = blockIdx.y * BM;
  const int col0 = blockIdx.x * BN;
  float acc[TM][TN];
#pragma unroll
  for (int i = 0; i < TM; ++i)
#pragma unroll
    for (int j = 0; j < TN; ++j) acc[i][j] = 0.f;
  for (int k0 = 0; k0 < K; k0 += BK) {
    __syncthreads();
    constexpr int AV = BM * BK / 4;
#pragma unroll
    for (int idx = tid; idx < AV; idx += 256) {
      int m = idx / (BK / 4);
      int kq = idx % (BK / 4);
      const float4 v = *reinterpret_cast<const float4*>(&A[(size_t)(row0 + m) * K + k0 + kq * 4]);
      As[kq * 4 + 0][m] = v.x; As[kq * 4 + 1][m] = v.y;
      As[kq * 4 + 2][m] = v.z; As[kq * 4 + 3][m] = v.w;
    }
    constexpr int BV = BK * BN / 4;
#pragma unroll
    for (int idx = tid; idx < BV; idx += 256) {
      int k = idx / (BN / 4);
      int nq = idx % (BN / 4);
      const float4 v = *reinterpret_cast<const float4*>(&B[(size_t)(k0 + k) * N + col0 + nq * 4]);
      *reinterpret_cast<float4*>(&Bs[k][nq * 4]) = v;
    }
    __syncthreads();
#pragma unroll
    for (int kk = 0; kk < BK; ++kk) {
      float a[TM], b[TN];
#pragma unroll
      for (int i = 0; i < TM; i += 4)
        *reinterpret_cast<float4*>(&a[i]) = *reinterpret_cast<const float4*>(&As[kk][trow * TM + i]);
#pragma unroll
      for (int j = 0; j < TN; j += 4)
        *reinterpret_cast<float4*>(&b[j]) = *reinterpret_cast<const float4*>(&Bs[kk][tcol * TN + j]);
#pragma unroll
      for (int i = 0; i < TM; ++i)
#pragma unroll
        for (int j = 0; j < TN; ++j) acc[i][j] = fmaf(a[i], b[j], acc[i][j]);
    }
  }
#pragma unroll
  for (int i = 0; i < TM; ++i)
#pragma unroll
    for (int j = 0; j < TN; j += 4) {
      float4 v = {acc[i][j], acc[i][j + 1], acc[i][j + 2], acc[i][j + 3]};
      *reinterpret_cast<float4*>(&C[(size_t)(row0 + trow * TM + i) * N + col0 + tcol * TN + j]) = v;
    }
}

// --- layer-2 attention scores (heads=1, K=HD)
__global__ __launch_bounds__(256) void att_scores2(
    const float* __restrict__ h, const float* __restrict__ wa_s,
    const float* __restrict__ wa_d, float* __restrict__ a_src, float* __restrict__ a_dst) {
  __shared__ float ws[HD], wd[HD];
  for (int i = threadIdx.x; i < HD; i += 256) { ws[i] = wa_s[i]; wd[i] = wa_d[i]; }
  __syncthreads();
  int lane = threadIdx.x & 63;
  int row = blockIdx.x * 4 + (threadIdx.x >> 6);
  const float* hr = h + (size_t)row * HD;
  float p = 0.f, q = 0.f;
#pragma unroll
  for (int c0 = 0; c0 < HD; c0 += 64) {
    float v = hr[c0 + lane];
    p = fmaf(v, ws[c0 + lane], p);
    q = fmaf(v, wd[c0 + lane], q);
  }
#pragma unroll
  for (int off = 32; off; off >>= 1) p += __shfl_xor(p, off, 64);
  if (lane == 0) a_src[row] = p;
  if (row < N3) {
#pragma unroll
    for (int off = 32; off; off >>= 1) q += __shfl_xor(q, off, 64);
    if (lane == 0) a_dst[row] = q;
  }
}

// --- layer-2 aggregation: wave per dst node (4/block), writes d_out (+b2)
__global__ __launch_bounds__(256) void agg2(
    const int* __restrict__ rp, const int* __restrict__ srcs,
    const float* __restrict__ a_src, const float* __restrict__ a_dst,
    const float* __restrict__ h2, const float* __restrict__ b2,
    float* __restrict__ out) {
  int d = blockIdx.x * 4 + (threadIdx.x >> 6);
  int lane = threadIdx.x & 63;
  int beg = rp[d], end = rp[d + 1];
  float ad = a_dst[d];
  float m = -__builtin_inff(), ssum = 0.f, acc = 0.f;
  for (int base = beg; base < end; base += 64) {
    int cnt = end - base; if (cnt > 64) cnt = 64;
    int sidx = 0; float e = -__builtin_inff();
    if (lane < cnt) {
      sidx = srcs[base + lane];
      float t = a_src[sidx] + ad;
      e = t > 0.f ? t : NEG_SLOPE * t;
    }
    float cm = e;
#pragma unroll
    for (int off = 32; off; off >>= 1) cm = fmaxf(cm, __shfl_xor(cm, off, 64));
    float nm = fmaxf(m, cm);
    float p = (lane < cnt) ? __expf(e - nm) : 0.f;
    float ps = p;
#pragma unroll
    for (int off = 32; off; off >>= 1) ps += __shfl_xor(ps, off, 64);
    float scale = __expf(m - nm);
    acc *= scale;
    ssum = ssum * scale + ps;
    m = nm;
    for (int j = 0; j < cnt; ++j) {
      float pj = __shfl(p, j, 64);
      int sj = __shfl(sidx, j, 64);
      acc = fmaf(pj, h2[(size_t)sj * OUT_DIM + lane], acc);
    }
  }
  out[(size_t)d * OUT_DIM + lane] = acc / fmaxf(ssum, 1e-16f) + b2[lane];
}

extern "C" void kernel_launch(void* const* d_in, const int* in_sizes, int n_in,
                              void* d_out, int out_size, void* d_ws, size_t ws_size,
                              hipStream_t stream) {
  const float* x     = (const float*)d_in[0];
  const float* W1s   = (const float*)d_in[1];
  const float* W1d   = (const float*)d_in[2];
  const float* A1s   = (const float*)d_in[3];
  const float* A1d   = (const float*)d_in[4];
  const float* b1    = (const float*)d_in[5];
  const float* gamma = (const float*)d_in[6];
  const float* beta  = (const float*)d_in[7];
  const float* rmean = (const float*)d_in[8];
  const float* rvar  = (const float*)d_in[9];
  const float* W2s   = (const float*)d_in[10];
  const float* W2d   = (const float*)d_in[11];
  const float* A2s   = (const float*)d_in[12];
  const float* A2d   = (const float*)d_in[13];
  const float* b2    = (const float*)d_in[14];
  const int* src1    = (const int*)d_in[15];
  const int* dst1    = (const int*)d_in[16];
  const int* src2    = (const int*)d_in[17];
  const int* dst2    = (const int*)d_in[18];
  (void)in_sizes; (void)n_in; (void)out_size; (void)ws_size;

  char* W = (char*)d_ws;
  size_t off = 0;
  auto alloc = [&](size_t bytes) { void* p = W + off; off = (off + bytes + 255) & ~(size_t)255; return p; };
  unsigned short* xbf  = (unsigned short*)alloc((size_t)N1 * IN_DIM * 2);
  unsigned short* w1T  = (unsigned short*)alloc((size_t)HD * IN_DIM * 2);
  unsigned short* h1   = (unsigned short*)alloc((size_t)N1 * HD * 2);
  float* a1s  = (float*)alloc((size_t)N1 * HEADS * 4);
  float* a1d  = (float*)alloc((size_t)N2 * HEADS * 4);
  int* deg1   = (int*)alloc((size_t)N2 * 4);
  int* rank1  = (int*)alloc((size_t)E1 * 4);
  int* rp1    = (int*)alloc((size_t)(N2 + 1) * 4);
  int* srcs1  = (int*)alloc((size_t)E1 * 4);
  float* acc1 = (float*)alloc((size_t)N2 * HD * 4);
  float* h2   = (float*)alloc((size_t)N2 * OUT_DIM * 4);
  float* a2s  = (float*)alloc((size_t)N2 * 4);
  float* a2d  = (float*)alloc((size_t)N3 * 4);
  int* deg2   = (int*)alloc((size_t)N3 * 4);
  int* rank2  = (int*)alloc((size_t)E2 * 4);
  int* rp2    = (int*)alloc((size_t)(N3 + 1) * 4);
  int* srcs2  = (int*)alloc((size_t)E2 * 4);
  float* wa1s = (float*)alloc(HEADS * IN_DIM * 4);
  float* wa1d = (float*)alloc(HEADS * IN_DIM * 4);
  float* wa2s = (float*)alloc(HD * 4);
  float* wa2d = (float*)alloc(HD * 4);
  int* bsums1 = (int*)alloc(64 * 4);
  int* bsums2 = (int*)alloc(64 * 4);

  precompute_wa<<<3, 256, 0, stream>>>(W1s, W1d, A1s, A1d, W2s, W2d, A2s, A2d,
                                       wa1s, wa1d, wa2s, wa2d);
  init_k<<<64, 256, 0, stream>>>(deg1, deg2, rp1, rp2);
  conv_w1T<<<16, 256, 0, stream>>>(W1s, w1T);

  // CSR graph 1
  hist_k<<<E1 / 256, 256, 0, stream>>>(dst1, deg1, rank1, E1);
  scan1_k<<<N2 / 1024, 256, 0, stream>>>(deg1, rp1 + 1, bsums1, N2);
  scan2_k<<<1, 256, 0, stream>>>(bsums1, N2 / 1024);
  scan3_k<<<N2 / 1024, 256, 0, stream>>>(rp1 + 1, bsums1, N2);
  scatter_k<<<E1 / 256, 256, 0, stream>>>(src1, dst1, rp1, rank1, srcs1, E1);
  // CSR graph 2
  hist_k<<<E2 / 256, 256, 0, stream>>>(dst2, deg2, rank2, E2);
  scan1_k<<<N3 / 1024, 256, 0, stream>>>(deg2, rp2 + 1, bsums2, N3);
  scan2_k<<<1, 256, 0, stream>>>(bsums2, N3 / 1024);
  scan3_k<<<N3 / 1024, 256, 0, stream>>>(rp2 + 1, bsums2, N3);
  scatter_k<<<E2 / 256, 256, 0, stream>>>(src2, dst2, rp2, rank2, srcs2, E2);

  // ---- layer 1 ----
  conv_scores1<<<N1 / 16, 256, 0, stream>>>(x, wa1s, wa1d, xbf, a1s, a1d);
  gemm1_bf16<<<dim3(HD / 128, N1 / 128), 256, 65536, stream>>>(xbf, w1T, h1);
  agg1<<<N2, 256, 0, stream>>>(rp1, srcs1, a1s, a1d, h1, b1, gamma, beta,
                               rmean, rvar, acc1);

  // ---- layer 2 ----
  sgemm<128, 64, 16, 8, 4><<<dim3(OUT_DIM / 64, N2 / 128), 256, 0, stream>>>(
      acc1, W2s, h2, N2, OUT_DIM, HD);
  att_scores2<<<N2 / 4, 256, 0, stream>>>(acc1, wa2s, wa2d, a2s, a2d);
  agg2<<<N3 / 4, 256, 0, stream>>>(rp2, srcs2, a2s, a2d, h2, b2, (float*)d_out);
}

// Round 3
// 535.046 us; speedup vs baseline: 2.5178x; 1.1226x over previous
//
#include <hip/hip_runtime.h>

// ---------------------------------------------------------------------------
// 2-layer bipartite GAT, MI355X / gfx950. Round 3:
//  - Layer-1 factorization: aggregate x (bf16, L3-resident) per dst/head with
//    online softmax -> z[4][N2][128]; THEN project z @ W1_head (MFMA) with
//    fused bias+BN+ELU + fused layer-2 attention-score partial dots.
//    Eliminates the N1-sized GEMM and the h1 gather entirely.
//  - Layer-2 GEMM in bf16 MFMA (acc1 stored bf16, pre-swizzled).
// ---------------------------------------------------------------------------

constexpr int N1 = 262144, N2 = 65536, N3 = 16384;
constexpr int E1 = 524288, E2 = 262144;
constexpr int IN_DIM = 128, HID = 64, HEADS = 4, OUT_DIM = 64;
constexpr int HD = HEADS * HID;   // 256
constexpr float NEG_SLOPE = 0.2f;
constexpr float BN_EPS = 1e-5f;

typedef __attribute__((ext_vector_type(8))) short bf16x8;
typedef __attribute__((ext_vector_type(8))) unsigned short ushort8;
typedef __attribute__((ext_vector_type(4))) float f32x4;

#define GLOAD_LDS16(gp, lp)                                              \
  __builtin_amdgcn_global_load_lds(                                      \
      (const __attribute__((address_space(1))) unsigned int*)(gp),       \
      (__attribute__((address_space(3))) unsigned int*)(lp), 16, 0, 0)

__device__ inline unsigned short f2bf(float f) {   // RNE
  unsigned u = __float_as_uint(f);
  u += 0x7FFFu + ((u >> 16) & 1u);
  return (unsigned short)(u >> 16);
}
__device__ inline float bf2f(unsigned short s) {
  return __uint_as_float(((unsigned)s) << 16);
}

// --- fold att into W (wa[h][k]) + fold bias+BN into per-channel scale/shift
__global__ __launch_bounds__(256) void precompute_wa(
    const float* __restrict__ W1s, const float* __restrict__ W1d,
    const float* __restrict__ A1s, const float* __restrict__ A1d,
    const float* __restrict__ W2s, const float* __restrict__ W2d,
    const float* __restrict__ A2s, const float* __restrict__ A2d,
    const float* __restrict__ b1, const float* __restrict__ gamma,
    const float* __restrict__ beta, const float* __restrict__ mean,
    const float* __restrict__ var,
    float* __restrict__ wa1s, float* __restrict__ wa1d,
    float* __restrict__ wa2s, float* __restrict__ wa2d,
    float* __restrict__ bnsc, float* __restrict__ bnsh) {
  int t = blockIdx.x * 256 + threadIdx.x;
  if (t < HEADS * IN_DIM) {           // layout [h][k]
    int h = t >> 7, k = t & 127;
    float s = 0.f, d = 0.f;
    for (int c = 0; c < HID; ++c) {
      s += W1s[k * HD + h * HID + c] * A1s[h * HID + c];
      d += W1d[k * HD + h * HID + c] * A1d[h * HID + c];
    }
    wa1s[t] = s; wa1d[t] = d;
  } else if (t < HEADS * IN_DIM + HD) {
    int k = t - HEADS * IN_DIM;
    float s = 0.f, d = 0.f;
    for (int c = 0; c < OUT_DIM; ++c) {
      s += W2s[k * OUT_DIM + c] * A2s[c];
      d += W2d[k * OUT_DIM + c] * A2d[c];
    }
    wa2s[k] = s; wa2d[k] = d;
  } else if (t < HEADS * IN_DIM + 2 * HD) {
    int c = t - HEADS * IN_DIM - HD;
    float sc = gamma[c] * rsqrtf(var[c] + BN_EPS);
    bnsc[c] = sc;
    bnsh[c] = beta[c] + (b1[c] - mean[c]) * sc;
  }
}

__global__ void init_k(int* __restrict__ deg1, int* __restrict__ deg2,
                       int* __restrict__ rp1, int* __restrict__ rp2,
                       float* __restrict__ a2s, float* __restrict__ a2d) {
  int i = blockIdx.x * 256 + threadIdx.x;
  int stride = gridDim.x * 256;
  for (int j = i; j < N2; j += stride) { deg1[j] = 0; a2s[j] = 0.f; }
  for (int j = i; j < N3; j += stride) { deg2[j] = 0; a2d[j] = 0.f; }
  if (i == 0) { rp1[0] = 0; rp2[0] = 0; }
}

// --- CSR build ---
__global__ __launch_bounds__(256) void hist_k(const int* __restrict__ dst,
                                              int* __restrict__ deg,
                                              int* __restrict__ rank, int E) {
  int i = blockIdx.x * 256 + threadIdx.x;
  if (i < E) rank[i] = atomicAdd(&deg[dst[i]], 1);
}

__global__ __launch_bounds__(256) void scan1_k(const int* __restrict__ in,
                                               int* __restrict__ out,
                                               int* __restrict__ bsums, int n) {
  __shared__ int s[256];
  int b = blockIdx.x, tid = threadIdx.x;
  int i0 = b * 1024 + tid * 4;
  int x0 = (i0 < n) ? in[i0] : 0;
  int x1 = (i0 + 1 < n) ? in[i0 + 1] : 0;
  int x2 = (i0 + 2 < n) ? in[i0 + 2] : 0;
  int x3 = (i0 + 3 < n) ? in[i0 + 3] : 0;
  int t = x0 + x1 + x2 + x3;
  s[tid] = t;
  __syncthreads();
  for (int off = 1; off < 256; off <<= 1) {
    int v = (tid >= off) ? s[tid - off] : 0;
    __syncthreads();
    s[tid] += v;
    __syncthreads();
  }
  int base = s[tid] - t;
  if (i0 < n) out[i0] = base + x0;
  if (i0 + 1 < n) out[i0 + 1] = base + x0 + x1;
  if (i0 + 2 < n) out[i0 + 2] = base + x0 + x1 + x2;
  if (i0 + 3 < n) out[i0 + 3] = base + t;
  if (tid == 255) bsums[b] = s[255];
}

__global__ void scan2_k(int* __restrict__ bs, int nb) {
  __shared__ int s[256];
  int tid = threadIdx.x;
  s[tid] = (tid < nb) ? bs[tid] : 0;
  __syncthreads();
  for (int off = 1; off < 256; off <<= 1) {
    int v = (tid >= off) ? s[tid - off] : 0;
    __syncthreads();
    s[tid] += v;
    __syncthreads();
  }
  if (tid < nb) bs[tid] = s[tid];
}

__global__ __launch_bounds__(256) void scan3_k(int* __restrict__ out,
                                               const int* __restrict__ bs, int n) {
  int b = blockIdx.x;
  if (b == 0) return;
  int add = bs[b - 1];
  int i0 = b * 1024 + threadIdx.x * 4;
  if (i0 < n) out[i0] += add;
  if (i0 + 1 < n) out[i0 + 1] += add;
  if (i0 + 2 < n) out[i0 + 2] += add;
  if (i0 + 3 < n) out[i0 + 3] += add;
}

__global__ __launch_bounds__(256) void scatter_k(const int* __restrict__ src,
                                                 const int* __restrict__ dst,
                                                 const int* __restrict__ rp,
                                                 const int* __restrict__ rank,
                                                 int* __restrict__ srcs, int E) {
  int i = blockIdx.x * 256 + threadIdx.x;
  if (i < E) srcs[rp[dst[i]] + rank[i]] = src[i];
}

// --- fused: x -> bf16 (linear) + layer-1 attention scores
__global__ __launch_bounds__(256) void conv_scores1(
    const float* __restrict__ x, const float* __restrict__ wa_s,
    const float* __restrict__ wa_d, unsigned short* __restrict__ xbf,
    float* __restrict__ a_src, float* __restrict__ a_dst) {
  __shared__ float ws[HEADS * IN_DIM], wd[HEADS * IN_DIM];
  int tid = threadIdx.x;
  for (int i = tid; i < HEADS * IN_DIM; i += 256) { ws[i] = wa_s[i]; wd[i] = wa_d[i]; }
  __syncthreads();
  int row = blockIdx.x * 16 + (tid >> 4);
  int g = tid & 15;
  float4 v0 = *reinterpret_cast<const float4*>(x + (size_t)row * IN_DIM + g * 8);
  float4 v1 = *reinterpret_cast<const float4*>(x + (size_t)row * IN_DIM + g * 8 + 4);
  float xv[8] = {v0.x, v0.y, v0.z, v0.w, v1.x, v1.y, v1.z, v1.w};
  ushort8 o;
#pragma unroll
  for (int j = 0; j < 8; ++j) o[j] = f2bf(xv[j]);
  *reinterpret_cast<ushort8*>(xbf + (size_t)row * IN_DIM + g * 8) = o;
#pragma unroll
  for (int h = 0; h < HEADS; ++h) {
    float p = 0.f;
#pragma unroll
    for (int j = 0; j < 8; ++j) p = fmaf(xv[j], ws[h * IN_DIM + g * 8 + j], p);
#pragma unroll
    for (int off = 1; off < 16; off <<= 1) p += __shfl_xor(p, off, 64);
    if (g == 0) a_src[(size_t)row * HEADS + h] = p;
  }
  if (row < N2) {
#pragma unroll
    for (int h = 0; h < HEADS; ++h) {
      float p = 0.f;
#pragma unroll
      for (int j = 0; j < 8; ++j) p = fmaf(xv[j], wd[h * IN_DIM + g * 8 + j], p);
#pragma unroll
      for (int off = 1; off < 16; off <<= 1) p += __shfl_xor(p, off, 64);
      if (g == 0) a_dst[(size_t)row * HEADS + h] = p;
    }
  }
}

// --- W1_src -> bf16, transposed [256 cols][128 k], row-swizzled (key n&7)
__global__ __launch_bounds__(256) void conv_w1T(const float* __restrict__ W,
                                                unsigned short* __restrict__ WT) {
  int t = blockIdx.x * 256 + threadIdx.x;   // [0, 256*16)
  int n = t >> 4, g = t & 15;
  ushort8 o;
#pragma unroll
  for (int j = 0; j < 8; ++j) o[j] = f2bf(W[(size_t)(g * 8 + j) * HD + n]);
  *reinterpret_cast<ushort8*>(WT + (size_t)n * IN_DIM + (size_t)(g ^ (n & 7)) * 8) = o;
}

// --- W2_src -> bf16, transposed [64 cols][256 k], half-swizzled (key n&7)
__global__ __launch_bounds__(256) void conv_w2T(const float* __restrict__ W,
                                                unsigned short* __restrict__ WT) {
  int t = blockIdx.x * 256 + threadIdx.x;   // [0, 64*32)
  int n = t >> 5, G = t & 31;
  int k0 = G * 8;
  ushort8 o;
#pragma unroll
  for (int j = 0; j < 8; ++j) o[j] = f2bf(W[(size_t)(k0 + j) * OUT_DIM + n]);
  int idx = ((k0 >> 7) << 7) + ((k0 & 127) ^ ((n & 7) << 3));
  *reinterpret_cast<ushort8*>(WT + (size_t)n * HD + idx) = o;
}

// --- layer-1 x-aggregation: block per dst node, wave = head, online softmax.
//     z[h][N2][128] bf16, groups XOR-swizzled by (d&7) for MFMA staging.
__global__ __launch_bounds__(256) void agg1x(
    const int* __restrict__ rp, const int* __restrict__ srcs,
    const float* __restrict__ a_src, const float* __restrict__ a_dst,
    const unsigned short* __restrict__ xbf, unsigned short* __restrict__ z) {
  int d = blockIdx.x;
  int h = threadIdx.x >> 6, lane = threadIdx.x & 63;
  int beg = rp[d], end = rp[d + 1];
  float ad = a_dst[(size_t)d * HEADS + h];
  float m = -__builtin_inff(), ssum = 0.f, z0 = 0.f, z1 = 0.f;
  for (int base = beg; base < end; base += 64) {
    int cnt = end - base; if (cnt > 64) cnt = 64;
    int sidx = 0; float e = -__builtin_inff();
    if (lane < cnt) {
      sidx = srcs[base + lane];
      float t = a_src[(size_t)sidx * HEADS + h] + ad;
      e = t > 0.f ? t : NEG_SLOPE * t;
    }
    float cm = e;
#pragma unroll
    for (int off = 32; off; off >>= 1) cm = fmaxf(cm, __shfl_xor(cm, off, 64));
    float nm = fmaxf(m, cm);
    float p = (lane < cnt) ? __expf(e - nm) : 0.f;
    float ps = p;
#pragma unroll
    for (int off = 32; off; off >>= 1) ps += __shfl_xor(ps, off, 64);
    float scale = __expf(m - nm);   // first chunk: exp(-inf)=0
    z0 *= scale; z1 *= scale;
    ssum = ssum * scale + ps;
    m = nm;
    for (int j = 0; j < cnt; ++j) {
      float pj = __shfl(p, j, 64);
      int sj = __shfl(sidx, j, 64);
      unsigned v = ((const unsigned*)(xbf + (size_t)sj * IN_DIM))[lane];
      z0 = fmaf(pj, bf2f((unsigned short)(v & 0xffff)), z0);
      z1 = fmaf(pj, bf2f((unsigned short)(v >> 16)), z1);
    }
  }
  float inv = 1.f / fmaxf(ssum, 1e-16f);
  z0 *= inv; z1 *= inv;
  unsigned out = (unsigned)f2bf(z0) | ((unsigned)f2bf(z1) << 16);
  int G = lane >> 2;
  int idx = ((G ^ (d & 7)) << 3) + ((lane & 3) << 1);
  *reinterpret_cast<unsigned*>(z + ((size_t)h * N2 + d) * IN_DIM + idx) = out;
}

// --- finalize layer 1: acc1[d, h*64+c] = ELU(BN(z_h[d,:] . W1_h[:,c]))
//     MFMA 16x16x32; fused layer-2 attention-score partial dots (atomicAdd).
//     acc1 written bf16, half-swizzled by (row&7) for gemm2 staging.
__global__ __launch_bounds__(256) void finalize1(
    const unsigned short* __restrict__ z, const unsigned short* __restrict__ w1T,
    const float* __restrict__ bnsc, const float* __restrict__ bnsh,
    const float* __restrict__ wa2s, const float* __restrict__ wa2d,
    unsigned short* __restrict__ acc1, float* __restrict__ a2s,
    float* __restrict__ a2d) {
  __shared__ char sm[49152];   // A: 32 KB @0, B: 16 KB @32768
  const int tid = threadIdx.x, wave = tid >> 6, lane = tid & 63;
  const int row0 = blockIdx.x * 128;
  const int h = blockIdx.y;
  const char* gA = (const char*)(z + ((size_t)h * N2 + row0) * IN_DIM);
  const char* gB = (const char*)(w1T + (size_t)h * 64 * IN_DIM);
#pragma unroll
  for (int it = 0; it < 8; ++it) {
    int off = it * 4096 + wave * 1024 + lane * 16;
    GLOAD_LDS16(gA + off, sm + off);
  }
#pragma unroll
  for (int it = 0; it < 4; ++it) {
    int off = it * 4096 + wave * 1024 + lane * 16;
    GLOAD_LDS16(gB + off, sm + 32768 + off);
  }
  __syncthreads();
  const int rbase = wave * 32;
  const int kl = (lane >> 4) * 8, fr = lane & 15;
  f32x4 acc[2][4] = {};
#pragma unroll
  for (int ks = 0; ks < 4; ++ks) {
    int k0 = ks * 32 + kl;
    bf16x8 a[2], b[4];
#pragma unroll
    for (int i = 0; i < 2; ++i) {
      int ra = rbase + i * 16 + fr;
      a[i] = *reinterpret_cast<const bf16x8*>(
          sm + ((size_t)ra * 128 + (k0 ^ ((ra & 7) << 3))) * 2);
    }
#pragma unroll
    for (int j = 0; j < 4; ++j) {
      int cb = j * 16 + fr;
      b[j] = *reinterpret_cast<const bf16x8*>(
          sm + 32768 + ((size_t)cb * 128 + (k0 ^ ((cb & 7) << 3))) * 2);
    }
#pragma unroll
    for (int i = 0; i < 2; ++i)
#pragma unroll
      for (int j = 0; j < 4; ++j)
        acc[i][j] = __builtin_amdgcn_mfma_f32_16x16x32_bf16(a[i], b[j], acc[i][j], 0, 0, 0);
  }
  // epilogue: BN+ELU, bf16 write (swizzled), fused att2 partial dots
  float sc[4], sh[4], w2sv[4], w2dv[4];
#pragma unroll
  for (int j = 0; j < 4; ++j) {
    int c = h * 64 + j * 16 + fr;
    sc[j] = bnsc[c]; sh[j] = bnsh[c]; w2sv[j] = wa2s[c]; w2dv[j] = wa2d[c];
  }
  const int g = lane >> 4;
#pragma unroll
  for (int i = 0; i < 2; ++i) {
#pragma unroll
    for (int q = 0; q < 4; ++q) {
      int row = row0 + rbase + i * 16 + g * 4 + q;
      float s2s = 0.f, s2d = 0.f;
#pragma unroll
      for (int j = 0; j < 4; ++j) {
        float v = acc[i][j][q] * sc[j] + sh[j];
        v = v > 0.f ? v : expm1f(v);
        s2s = fmaf(v, w2sv[j], s2s);
        s2d = fmaf(v, w2dv[j], s2d);
        int c = h * 64 + j * 16 + fr;
        int idx = ((c >> 7) << 7) + ((c & 127) ^ ((row & 7) << 3));
        acc1[(size_t)row * HD + idx] = f2bf(v);
      }
#pragma unroll
      for (int off = 1; off < 16; off <<= 1) {
        s2s += __shfl_xor(s2s, off, 64);
        s2d += __shfl_xor(s2d, off, 64);
      }
      if (fr == 0) {
        atomicAdd(&a2s[row], s2s);
        if (row < N3) atomicAdd(&a2d[row], s2d);
      }
    }
  }
}

// --- layer-2 GEMM: h2[N2][64] = acc1_bf16[N2][256] @ W2sT_bf16^T (fp32 out)
__global__ __launch_bounds__(256) void gemm2(
    const unsigned short* __restrict__ acc1, const unsigned short* __restrict__ w2T,
    float* __restrict__ h2) {
  __shared__ char sm[65536];   // A half-tile 32 KB @0, B full 32 KB @32768
  const int tid = threadIdx.x, wave = tid >> 6, lane = tid & 63;
  const int row0 = blockIdx.x * 128;
  const char* gB = (const char*)w2T;
#pragma unroll
  for (int it = 0; it < 8; ++it) {
    int off = it * 4096 + wave * 1024 + lane * 16;
    GLOAD_LDS16(gB + off, sm + 32768 + off);
  }
  const int rbase = wave * 32;
  const int kl = (lane >> 4) * 8, fr = lane & 15;
  f32x4 acc[2][4] = {};
  for (int kh = 0; kh < 2; ++kh) {
    __syncthreads();   // drains staged loads; protects A reuse
#pragma unroll
    for (int it = 0; it < 8; ++it) {
      int r = it * 16 + (tid >> 4);
      const char* src = (const char*)(acc1 + (size_t)(row0 + r) * HD) +
                        kh * 256 + (tid & 15) * 16;
      GLOAD_LDS16(src, sm + it * 4096 + tid * 16);
    }
    __syncthreads();
#pragma unroll
    for (int ks = 0; ks < 4; ++ks) {
      int k0 = ks * 32 + kl;
      bf16x8 a[2], b[4];
#pragma unroll
      for (int i = 0; i < 2; ++i) {
        int ra = rbase + i * 16 + fr;
        a[i] = *reinterpret_cast<const bf16x8*>(
            sm + ((size_t)ra * 128 + (k0 ^ ((ra & 7) << 3))) * 2);
      }
#pragma unroll
      for (int j = 0; j < 4; ++j) {
        int cb = j * 16 + fr;
        b[j] = *reinterpret_cast<const bf16x8*>(
            sm + 32768 + ((size_t)cb * 256 + kh * 128 + (k0 ^ ((cb & 7) << 3))) * 2);
      }
#pragma unroll
      for (int i = 0; i < 2; ++i)
#pragma unroll
        for (int j = 0; j < 4; ++j)
          acc[i][j] = __builtin_amdgcn_mfma_f32_16x16x32_bf16(a[i], b[j], acc[i][j], 0, 0, 0);
    }
  }
  const int g = lane >> 4;
#pragma unroll
  for (int i = 0; i < 2; ++i)
#pragma unroll
    for (int q = 0; q < 4; ++q) {
      int row = row0 + rbase + i * 16 + g * 4 + q;
#pragma unroll
      for (int j = 0; j < 4; ++j)
        h2[(size_t)row * OUT_DIM + j * 16 + fr] = acc[i][j][q];
    }
}

// --- layer-2 aggregation: wave per dst node, writes d_out (+b2)
__global__ __launch_bounds__(256) void agg2(
    const int* __restrict__ rp, const int* __restrict__ srcs,
    const float* __restrict__ a_src, const float* __restrict__ a_dst,
    const float* __restrict__ h2, const float* __restrict__ b2,
    float* __restrict__ out) {
  int d = blockIdx.x * 4 + (threadIdx.x >> 6);
  int lane = threadIdx.x & 63;
  int beg = rp[d], end = rp[d + 1];
  float ad = a_dst[d];
  float m = -__builtin_inff(), ssum = 0.f, acc = 0.f;
  for (int base = beg; base < end; base += 64) {
    int cnt = end - base; if (cnt > 64) cnt = 64;
    int sidx = 0; float e = -__builtin_inff();
    if (lane < cnt) {
      sidx = srcs[base + lane];
      float t = a_src[sidx] + ad;
      e = t > 0.f ? t : NEG_SLOPE * t;
    }
    float cm = e;
#pragma unroll
    for (int off = 32; off; off >>= 1) cm = fmaxf(cm, __shfl_xor(cm, off, 64));
    float nm = fmaxf(m, cm);
    float p = (lane < cnt) ? __expf(e - nm) : 0.f;
    float ps = p;
#pragma unroll
    for (int off = 32; off; off >>= 1) ps += __shfl_xor(ps, off, 64);
    float scale = __expf(m - nm);
    acc *= scale;
    ssum = ssum * scale + ps;
    m = nm;
    for (int j = 0; j < cnt; ++j) {
      float pj = __shfl(p, j, 64);
      int sj = __shfl(sidx, j, 64);
      acc = fmaf(pj, h2[(size_t)sj * OUT_DIM + lane], acc);
    }
  }
  out[(size_t)d * OUT_DIM + lane] = acc / fmaxf(ssum, 1e-16f) + b2[lane];
}

extern "C" void kernel_launch(void* const* d_in, const int* in_sizes, int n_in,
                              void* d_out, int out_size, void* d_ws, size_t ws_size,
                              hipStream_t stream) {
  const float* x     = (const float*)d_in[0];
  const float* W1s   = (const float*)d_in[1];
  const float* W1d   = (const float*)d_in[2];
  const float* A1s   = (const float*)d_in[3];
  const float* A1d   = (const float*)d_in[4];
  const float* b1    = (const float*)d_in[5];
  const float* gamma = (const float*)d_in[6];
  const float* beta  = (const float*)d_in[7];
  const float* rmean = (const float*)d_in[8];
  const float* rvar  = (const float*)d_in[9];
  const float* W2s   = (const float*)d_in[10];
  const float* W2d   = (const float*)d_in[11];
  const float* A2s   = (const float*)d_in[12];
  const float* A2d   = (const float*)d_in[13];
  const float* b2    = (const float*)d_in[14];
  const int* src1    = (const int*)d_in[15];
  const int* dst1    = (const int*)d_in[16];
  const int* src2    = (const int*)d_in[17];
  const int* dst2    = (const int*)d_in[18];
  (void)in_sizes; (void)n_in; (void)out_size; (void)ws_size;

  char* W = (char*)d_ws;
  size_t off = 0;
  auto alloc = [&](size_t bytes) { void* p = W + off; off = (off + bytes + 255) & ~(size_t)255; return p; };
  unsigned short* xbf = (unsigned short*)alloc((size_t)N1 * IN_DIM * 2);
  unsigned short* z   = (unsigned short*)alloc((size_t)HEADS * N2 * IN_DIM * 2);
  unsigned short* w1T = (unsigned short*)alloc((size_t)HD * IN_DIM * 2);
  unsigned short* w2T = (unsigned short*)alloc((size_t)OUT_DIM * HD * 2);
  unsigned short* acc1 = (unsigned short*)alloc((size_t)N2 * HD * 2);
  float* h2   = (float*)alloc((size_t)N2 * OUT_DIM * 4);
  float* a1s  = (float*)alloc((size_t)N1 * HEADS * 4);
  float* a1d  = (float*)alloc((size_t)N2 * HEADS * 4);
  float* a2s  = (float*)alloc((size_t)N2 * 4);
  float* a2d  = (float*)alloc((size_t)N3 * 4);
  int* deg1   = (int*)alloc((size_t)N2 * 4);
  int* rank1  = (int*)alloc((size_t)E1 * 4);
  int* rp1    = (int*)alloc((size_t)(N2 + 1) * 4);
  int* srcs1  = (int*)alloc((size_t)E1 * 4);
  int* deg2   = (int*)alloc((size_t)N3 * 4);
  int* rank2  = (int*)alloc((size_t)E2 * 4);
  int* rp2    = (int*)alloc((size_t)(N3 + 1) * 4);
  int* srcs2  = (int*)alloc((size_t)E2 * 4);
  float* wa1s = (float*)alloc(HEADS * IN_DIM * 4);
  float* wa1d = (float*)alloc(HEADS * IN_DIM * 4);
  float* wa2s = (float*)alloc(HD * 4);
  float* wa2d = (float*)alloc(HD * 4);
  float* bnsc = (float*)alloc(HD * 4);
  float* bnsh = (float*)alloc(HD * 4);
  int* bsums1 = (int*)alloc(64 * 4);
  int* bsums2 = (int*)alloc(64 * 4);

  precompute_wa<<<4, 256, 0, stream>>>(W1s, W1d, A1s, A1d, W2s, W2d, A2s, A2d,
                                       b1, gamma, beta, rmean, rvar,
                                       wa1s, wa1d, wa2s, wa2d, bnsc, bnsh);
  init_k<<<64, 256, 0, stream>>>(deg1, deg2, rp1, rp2, a2s, a2d);
  conv_w1T<<<16, 256, 0, stream>>>(W1s, w1T);
  conv_w2T<<<8, 256, 0, stream>>>(W2s, w2T);

  // CSR graph 1
  hist_k<<<E1 / 256, 256, 0, stream>>>(dst1, deg1, rank1, E1);
  scan1_k<<<N2 / 1024, 256, 0, stream>>>(deg1, rp1 + 1, bsums1, N2);
  scan2_k<<<1, 256, 0, stream>>>(bsums1, N2 / 1024);
  scan3_k<<<N2 / 1024, 256, 0, stream>>>(rp1 + 1, bsums1, N2);
  scatter_k<<<E1 / 256, 256, 0, stream>>>(src1, dst1, rp1, rank1, srcs1, E1);
  // CSR graph 2
  hist_k<<<E2 / 256, 256, 0, stream>>>(dst2, deg2, rank2, E2);
  scan1_k<<<N3 / 1024, 256, 0, stream>>>(deg2, rp2 + 1, bsums2, N3);
  scan2_k<<<1, 256, 0, stream>>>(bsums2, N3 / 1024);
  scan3_k<<<N3 / 1024, 256, 0, stream>>>(rp2 + 1, bsums2, N3);
  scatter_k<<<E2 / 256, 256, 0, stream>>>(src2, dst2, rp2, rank2, srcs2, E2);

  // ---- layer 1 (factored) ----
  conv_scores1<<<N1 / 16, 256, 0, stream>>>(x, wa1s, wa1d, xbf, a1s, a1d);
  agg1x<<<N2, 256, 0, stream>>>(rp1, srcs1, a1s, a1d, xbf, z);
  finalize1<<<dim3(N2 / 128, HEADS), 256, 0, stream>>>(
      z, w1T, bnsc, bnsh, wa2s, wa2d, acc1, a2s, a2d);

  // ---- layer 2 ----
  gemm2<<<N2 / 128, 256, 0, stream>>>(acc1, w2T, h2);
  agg2<<<N3 / 4, 256, 0, stream>>>(rp2, srcs2, a2s, a2d, h2, b2, (float*)d_out);
}

// Round 5
// 423.977 us; speedup vs baseline: 3.1774x; 1.2620x over previous
//
#include <hip/hip_runtime.h>

// ---------------------------------------------------------------------------
// 2-layer bipartite GAT, MI355X / gfx950. Round 4 (resubmit — infra timeout):
//  - No-max softmax (exact: shift-invariant, e bounded; denom >= ~exp(-15)>0)
//  - p=exp(leaky(e)) precomputed edge-parallel in the CSR scatter kernels;
//    aggregation is a single pass, zero shuffles, all 4 heads per wave,
//    gathers fp32 x rows directly (L3-resident).
//  - Launch consolidation: 12 dispatches.
// ---------------------------------------------------------------------------

constexpr int N1 = 262144, N2 = 65536, N3 = 16384;
constexpr int E1 = 524288, E2 = 262144;
constexpr int IN_DIM = 128, HID = 64, HEADS = 4, OUT_DIM = 64;
constexpr int HD = HEADS * HID;   // 256
constexpr float NEG_SLOPE = 0.2f;
constexpr float BN_EPS = 1e-5f;

typedef __attribute__((ext_vector_type(8))) short bf16x8;
typedef __attribute__((ext_vector_type(8))) unsigned short ushort8;
typedef __attribute__((ext_vector_type(4))) float f32x4;

#define GLOAD_LDS16(gp, lp)                                              \
  __builtin_amdgcn_global_load_lds(                                      \
      (const __attribute__((address_space(1))) unsigned int*)(gp),       \
      (__attribute__((address_space(3))) unsigned int*)(lp), 16, 0, 0)

__device__ inline unsigned short f2bf(float f) {   // RNE
  unsigned u = __float_as_uint(f);
  u += 0x7FFFu + ((u >> 16) & 1u);
  return (unsigned short)(u >> 16);
}

// === setup: wa folds + bn folds + init + weight transposes (92 blocks) ===
__global__ __launch_bounds__(256) void setup_k(
    const float* __restrict__ W1s, const float* __restrict__ W1d,
    const float* __restrict__ A1s, const float* __restrict__ A1d,
    const float* __restrict__ W2s, const float* __restrict__ W2d,
    const float* __restrict__ A2s, const float* __restrict__ A2d,
    const float* __restrict__ b1, const float* __restrict__ gamma,
    const float* __restrict__ beta, const float* __restrict__ mean,
    const float* __restrict__ var,
    float* __restrict__ wa1s, float* __restrict__ wa1d,
    float* __restrict__ wa2s, float* __restrict__ wa2d,
    float* __restrict__ bnsc, float* __restrict__ bnsh,
    int* __restrict__ deg1, int* __restrict__ deg2,
    int* __restrict__ rp1, int* __restrict__ rp2,
    float* __restrict__ a2s, float* __restrict__ a2d,
    unsigned short* __restrict__ w1T, unsigned short* __restrict__ w2T) {
  int b = blockIdx.x, tid = threadIdx.x;
  if (b < 4) {
    int t = b * 256 + tid;
    if (t < HEADS * IN_DIM) {           // wa1 layout [h][k]
      int h = t >> 7, k = t & 127;
      float s = 0.f, d = 0.f;
      for (int c = 0; c < HID; ++c) {
        s += W1s[k * HD + h * HID + c] * A1s[h * HID + c];
        d += W1d[k * HD + h * HID + c] * A1d[h * HID + c];
      }
      wa1s[t] = s; wa1d[t] = d;
    } else if (t < HEADS * IN_DIM + HD) {
      int k = t - HEADS * IN_DIM;
      float s = 0.f, d = 0.f;
      for (int c = 0; c < OUT_DIM; ++c) {
        s += W2s[k * OUT_DIM + c] * A2s[c];
        d += W2d[k * OUT_DIM + c] * A2d[c];
      }
      wa2s[k] = s; wa2d[k] = d;
    } else if (t < HEADS * IN_DIM + 2 * HD) {
      int c = t - HEADS * IN_DIM - HD;
      float sc = gamma[c] * rsqrtf(var[c] + BN_EPS);
      bnsc[c] = sc;
      bnsh[c] = beta[c] + (b1[c] - mean[c]) * sc;
    }
  } else if (b < 68) {
    int i = (b - 4) * 256 + tid;
    int stride = 64 * 256;
    for (int j = i; j < N2; j += stride) { deg1[j] = 0; a2s[j] = 0.f; }
    for (int j = i; j < N3; j += stride) { deg2[j] = 0; a2d[j] = 0.f; }
    if (i == 0) { rp1[0] = 0; rp2[0] = 0; }
  } else if (b < 84) {
    // W1_src -> bf16 transposed [256 n][128 k], group-swizzled by n&7
    int t = (b - 68) * 256 + tid;
    int n = t >> 4, g = t & 15;
    ushort8 o;
#pragma unroll
    for (int j = 0; j < 8; ++j) o[j] = f2bf(W1s[(size_t)(g * 8 + j) * HD + n]);
    *reinterpret_cast<ushort8*>(w1T + (size_t)n * IN_DIM + (size_t)(g ^ (n & 7)) * 8) = o;
  } else {
    // W2_src -> bf16 transposed [64 n][256 k], half-swizzled by n&7
    int t = (b - 84) * 256 + tid;
    int n = t >> 5, G = t & 31;
    int k0 = G * 8;
    ushort8 o;
#pragma unroll
    for (int j = 0; j < 8; ++j) o[j] = f2bf(W2s[(size_t)(k0 + j) * OUT_DIM + n]);
    int idx = ((k0 >> 7) << 7) + ((k0 & 127) ^ ((n & 7) << 3));
    *reinterpret_cast<ushort8*>(w2T + (size_t)n * HD + idx) = o;
  }
}

// === CSR: histogram both graphs ===
__global__ __launch_bounds__(256) void hist12_k(
    const int* __restrict__ dst1, int* __restrict__ deg1, int* __restrict__ rank1,
    const int* __restrict__ dst2, int* __restrict__ deg2, int* __restrict__ rank2) {
  int b = blockIdx.x;
  if (b < E1 / 256) {
    int i = b * 256 + threadIdx.x;
    rank1[i] = atomicAdd(&deg1[dst1[i]], 1);
  } else {
    int i = (b - E1 / 256) * 256 + threadIdx.x;
    rank2[i] = atomicAdd(&deg2[dst2[i]], 1);
  }
}

// === scans (both graphs fused per stage) ===
__device__ inline void scan_body(const int* in, int* out, int* bsums, int n, int b) {
  __shared__ int s[256];
  int tid = threadIdx.x;
  int i0 = b * 1024 + tid * 4;
  int x0 = in[i0], x1 = in[i0 + 1], x2 = in[i0 + 2], x3 = in[i0 + 3];
  int t = x0 + x1 + x2 + x3;
  s[tid] = t;
  __syncthreads();
  for (int off = 1; off < 256; off <<= 1) {
    int v = (tid >= off) ? s[tid - off] : 0;
    __syncthreads();
    s[tid] += v;
    __syncthreads();
  }
  int base = s[tid] - t;
  out[i0] = base + x0;
  out[i0 + 1] = base + x0 + x1;
  out[i0 + 2] = base + x0 + x1 + x2;
  out[i0 + 3] = base + t;
  if (tid == 255) bsums[b] = s[255];
  (void)n;
}

__global__ __launch_bounds__(256) void scanA_k(
    const int* __restrict__ deg1, int* __restrict__ o1, int* __restrict__ bs1,
    const int* __restrict__ deg2, int* __restrict__ o2, int* __restrict__ bs2) {
  int b = blockIdx.x;
  if (b < 64) scan_body(deg1, o1, bs1, N2, b);
  else scan_body(deg2, o2, bs2, N3, b - 64);
}

__global__ void scanB_k(int* __restrict__ bs1, int* __restrict__ bs2) {
  __shared__ int s[256];
  int* bs = (blockIdx.x == 0) ? bs1 : bs2;
  int nb = (blockIdx.x == 0) ? 64 : 16;
  int tid = threadIdx.x;
  s[tid] = (tid < nb) ? bs[tid] : 0;
  __syncthreads();
  for (int off = 1; off < 256; off <<= 1) {
    int v = (tid >= off) ? s[tid - off] : 0;
    __syncthreads();
    s[tid] += v;
    __syncthreads();
  }
  if (tid < nb) bs[tid] = s[tid];
}

__global__ __launch_bounds__(256) void scanC_k(
    int* __restrict__ o1, const int* __restrict__ bs1,
    int* __restrict__ o2, const int* __restrict__ bs2) {
  int b = blockIdx.x;
  int* out; const int* bs; int bb;
  if (b < 64) { out = o1; bs = bs1; bb = b; }
  else { out = o2; bs = bs2; bb = b - 64; }
  if (bb == 0) return;
  int add = bs[bb - 1];
  int i0 = bb * 1024 + threadIdx.x * 4;
  out[i0] += add; out[i0 + 1] += add; out[i0 + 2] += add; out[i0 + 3] += add;
}

// === fused: layer-1 attention scores (x stays fp32; no conversion pass) ===
__global__ __launch_bounds__(256) void conv_scores1(
    const float* __restrict__ x, const float* __restrict__ wa_s,
    const float* __restrict__ wa_d, float* __restrict__ a_src,
    float* __restrict__ a_dst) {
  __shared__ float ws[HEADS * IN_DIM], wd[HEADS * IN_DIM];
  int tid = threadIdx.x;
  for (int i = tid; i < HEADS * IN_DIM; i += 256) { ws[i] = wa_s[i]; wd[i] = wa_d[i]; }
  __syncthreads();
  int row = blockIdx.x * 16 + (tid >> 4);
  int g = tid & 15;
  float4 v0 = *reinterpret_cast<const float4*>(x + (size_t)row * IN_DIM + g * 8);
  float4 v1 = *reinterpret_cast<const float4*>(x + (size_t)row * IN_DIM + g * 8 + 4);
  float xv[8] = {v0.x, v0.y, v0.z, v0.w, v1.x, v1.y, v1.z, v1.w};
#pragma unroll
  for (int h = 0; h < HEADS; ++h) {
    float p = 0.f;
#pragma unroll
    for (int j = 0; j < 8; ++j) p = fmaf(xv[j], ws[h * IN_DIM + g * 8 + j], p);
#pragma unroll
    for (int off = 1; off < 16; off <<= 1) p += __shfl_xor(p, off, 64);
    if (g == 0) a_src[(size_t)row * HEADS + h] = p;
  }
  if (row < N2) {
#pragma unroll
    for (int h = 0; h < HEADS; ++h) {
      float p = 0.f;
#pragma unroll
      for (int j = 0; j < 8; ++j) p = fmaf(xv[j], wd[h * IN_DIM + g * 8 + j], p);
#pragma unroll
      for (int off = 1; off < 16; off <<= 1) p += __shfl_xor(p, off, 64);
      if (g == 0) a_dst[(size_t)row * HEADS + h] = p;
    }
  }
}

// === CSR scatter + edge weight p = exp(leaky(e)) (layer 1, 4 heads) ===
__global__ __launch_bounds__(256) void scatter1p_k(
    const int* __restrict__ src, const int* __restrict__ dst,
    const int* __restrict__ rp, const int* __restrict__ rank,
    const float* __restrict__ a1s, const float* __restrict__ a1d,
    int* __restrict__ srcs, float4* __restrict__ pexp) {
  int i = blockIdx.x * 256 + threadIdx.x;
  int s = src[i], d = dst[i];
  float4 as = *reinterpret_cast<const float4*>(a1s + (size_t)s * HEADS);
  float4 ad = *reinterpret_cast<const float4*>(a1d + (size_t)d * HEADS);
  float4 p;
#pragma unroll
  for (int h = 0; h < 4; ++h) {
    float e = ((const float*)&as)[h] + ((const float*)&ad)[h];
    e = e > 0.f ? e : NEG_SLOPE * e;
    ((float*)&p)[h] = __expf(e);
  }
  int pos = rp[d] + rank[i];
  srcs[pos] = s;
  pexp[pos] = p;
}

// === layer-1 aggregation: wave per dst (all 4 heads), single pass, no shfl.
//     z[h][N2][128] bf16, groups XOR-swizzled by (d&7) for MFMA staging. ===
__global__ __launch_bounds__(256) void agg1x(
    const int* __restrict__ rp, const int* __restrict__ srcs,
    const float4* __restrict__ pexp, const float* __restrict__ x,
    unsigned short* __restrict__ z) {
  int d = blockIdx.x * 4 + (threadIdx.x >> 6);
  int lane = threadIdx.x & 63;
  int beg = rp[d], end = rp[d + 1];
  float z0[4] = {0.f, 0.f, 0.f, 0.f}, z1[4] = {0.f, 0.f, 0.f, 0.f};
  float ss[4] = {0.f, 0.f, 0.f, 0.f}, ss2[4] = {0.f, 0.f, 0.f, 0.f};
  int j = beg;
  for (; j + 2 <= end; j += 2) {
    int s0 = srcs[j], s1 = srcs[j + 1];
    float4 p0 = pexp[j], p1 = pexp[j + 1];
    float2 v0 = *reinterpret_cast<const float2*>(x + (size_t)s0 * IN_DIM + lane * 2);
    float2 v1 = *reinterpret_cast<const float2*>(x + (size_t)s1 * IN_DIM + lane * 2);
#pragma unroll
    for (int h = 0; h < 4; ++h) {
      float ph0 = ((const float*)&p0)[h], ph1 = ((const float*)&p1)[h];
      z0[h] = fmaf(ph0, v0.x, fmaf(ph1, v1.x, z0[h]));
      z1[h] = fmaf(ph0, v0.y, fmaf(ph1, v1.y, z1[h]));
      ss[h] += ph0; ss2[h] += ph1;
    }
  }
  if (j < end) {
    int s0 = srcs[j];
    float4 p0 = pexp[j];
    float2 v0 = *reinterpret_cast<const float2*>(x + (size_t)s0 * IN_DIM + lane * 2);
#pragma unroll
    for (int h = 0; h < 4; ++h) {
      float ph0 = ((const float*)&p0)[h];
      z0[h] = fmaf(ph0, v0.x, z0[h]);
      z1[h] = fmaf(ph0, v0.y, z1[h]);
      ss[h] += ph0;
    }
  }
  int G = lane >> 2;
  int idx = ((G ^ (d & 7)) << 3) + ((lane & 3) << 1);
#pragma unroll
  for (int h = 0; h < 4; ++h) {
    float inv = 1.f / fmaxf(ss[h] + ss2[h], 1e-30f);
    unsigned out = (unsigned)f2bf(z0[h] * inv) | ((unsigned)f2bf(z1[h] * inv) << 16);
    *reinterpret_cast<unsigned*>(z + ((size_t)h * N2 + d) * IN_DIM + idx) = out;
  }
}

// === finalize layer 1: acc1 = ELU(BN(z_h @ W1_h)) via MFMA; fused layer-2
//     attention partial dots (atomicAdd). acc1 bf16, half-swizzled. ===
__global__ __launch_bounds__(256) void finalize1(
    const unsigned short* __restrict__ z, const unsigned short* __restrict__ w1T,
    const float* __restrict__ bnsc, const float* __restrict__ bnsh,
    const float* __restrict__ wa2s, const float* __restrict__ wa2d,
    unsigned short* __restrict__ acc1, float* __restrict__ a2s,
    float* __restrict__ a2d) {
  __shared__ char sm[49152];   // A: 32 KB @0, B: 16 KB @32768
  const int tid = threadIdx.x, wave = tid >> 6, lane = tid & 63;
  const int row0 = blockIdx.x * 128;
  const int h = blockIdx.y;
  const char* gA = (const char*)(z + ((size_t)h * N2 + row0) * IN_DIM);
  const char* gB = (const char*)(w1T + (size_t)h * 64 * IN_DIM);
#pragma unroll
  for (int it = 0; it < 8; ++it) {
    int off = it * 4096 + wave * 1024 + lane * 16;
    GLOAD_LDS16(gA + off, sm + off);
  }
#pragma unroll
  for (int it = 0; it < 4; ++it) {
    int off = it * 4096 + wave * 1024 + lane * 16;
    GLOAD_LDS16(gB + off, sm + 32768 + off);
  }
  __syncthreads();
  const int rbase = wave * 32;
  const int kl = (lane >> 4) * 8, fr = lane & 15;
  f32x4 acc[2][4] = {};
#pragma unroll
  for (int ks = 0; ks < 4; ++ks) {
    int k0 = ks * 32 + kl;
    bf16x8 a[2], b[4];
#pragma unroll
    for (int i = 0; i < 2; ++i) {
      int ra = rbase + i * 16 + fr;
      a[i] = *reinterpret_cast<const bf16x8*>(
          sm + ((size_t)ra * 128 + (k0 ^ ((ra & 7) << 3))) * 2);
    }
#pragma unroll
    for (int jj = 0; jj < 4; ++jj) {
      int cb = jj * 16 + fr;
      b[jj] = *reinterpret_cast<const bf16x8*>(
          sm + 32768 + ((size_t)cb * 128 + (k0 ^ ((cb & 7) << 3))) * 2);
    }
#pragma unroll
    for (int i = 0; i < 2; ++i)
#pragma unroll
      for (int jj = 0; jj < 4; ++jj)
        acc[i][jj] = __builtin_amdgcn_mfma_f32_16x16x32_bf16(a[i], b[jj], acc[i][jj], 0, 0, 0);
  }
  float sc[4], sh[4], w2sv[4], w2dv[4];
#pragma unroll
  for (int jj = 0; jj < 4; ++jj) {
    int c = h * 64 + jj * 16 + fr;
    sc[jj] = bnsc[c]; sh[jj] = bnsh[c]; w2sv[jj] = wa2s[c]; w2dv[jj] = wa2d[c];
  }
  const int g = lane >> 4;
#pragma unroll
  for (int i = 0; i < 2; ++i) {
#pragma unroll
    for (int q = 0; q < 4; ++q) {
      int row = row0 + rbase + i * 16 + g * 4 + q;
      float s2s = 0.f, s2d = 0.f;
#pragma unroll
      for (int jj = 0; jj < 4; ++jj) {
        float v = acc[i][jj][q] * sc[jj] + sh[jj];
        v = v > 0.f ? v : expm1f(v);
        s2s = fmaf(v, w2sv[jj], s2s);
        s2d = fmaf(v, w2dv[jj], s2d);
        int c = h * 64 + jj * 16 + fr;
        int idx = ((c >> 7) << 7) + ((c & 127) ^ ((row & 7) << 3));
        acc1[(size_t)row * HD + idx] = f2bf(v);
      }
#pragma unroll
      for (int off = 1; off < 16; off <<= 1) {
        s2s += __shfl_xor(s2s, off, 64);
        s2d += __shfl_xor(s2d, off, 64);
      }
      if (fr == 0) {
        atomicAdd(&a2s[row], s2s);
        if (row < N3) atomicAdd(&a2d[row], s2d);
      }
    }
  }
}

// === CSR scatter + p (layer 2, 1 head) — runs after finalize1 ===
__global__ __launch_bounds__(256) void scatter2p_k(
    const int* __restrict__ src, const int* __restrict__ dst,
    const int* __restrict__ rp, const int* __restrict__ rank,
    const float* __restrict__ a2s, const float* __restrict__ a2d,
    int* __restrict__ srcs, float* __restrict__ pexp) {
  int i = blockIdx.x * 256 + threadIdx.x;
  int s = src[i], d = dst[i];
  float e = a2s[s] + a2d[d];
  e = e > 0.f ? e : NEG_SLOPE * e;
  int pos = rp[d] + rank[i];
  srcs[pos] = s;
  pexp[pos] = __expf(e);
}

// === layer-2 GEMM: h2[N2][64] = acc1_bf16 @ W2sT^T (fp32 out) ===
__global__ __launch_bounds__(256) void gemm2(
    const unsigned short* __restrict__ acc1, const unsigned short* __restrict__ w2T,
    float* __restrict__ h2) {
  __shared__ char sm[65536];
  const int tid = threadIdx.x, wave = tid >> 6, lane = tid & 63;
  const int row0 = blockIdx.x * 128;
  const char* gB = (const char*)w2T;
#pragma unroll
  for (int it = 0; it < 8; ++it) {
    int off = it * 4096 + wave * 1024 + lane * 16;
    GLOAD_LDS16(gB + off, sm + 32768 + off);
  }
  const int rbase = wave * 32;
  const int kl = (lane >> 4) * 8, fr = lane & 15;
  f32x4 acc[2][4] = {};
  for (int kh = 0; kh < 2; ++kh) {
    __syncthreads();
#pragma unroll
    for (int it = 0; it < 8; ++it) {
      int r = it * 16 + (tid >> 4);
      const char* srcp = (const char*)(acc1 + (size_t)(row0 + r) * HD) +
                         kh * 256 + (tid & 15) * 16;
      GLOAD_LDS16(srcp, sm + it * 4096 + tid * 16);
    }
    __syncthreads();
#pragma unroll
    for (int ks = 0; ks < 4; ++ks) {
      int k0 = ks * 32 + kl;
      bf16x8 a[2], b[4];
#pragma unroll
      for (int i = 0; i < 2; ++i) {
        int ra = rbase + i * 16 + fr;
        a[i] = *reinterpret_cast<const bf16x8*>(
            sm + ((size_t)ra * 128 + (k0 ^ ((ra & 7) << 3))) * 2);
      }
#pragma unroll
      for (int jj = 0; jj < 4; ++jj) {
        int cb = jj * 16 + fr;
        b[jj] = *reinterpret_cast<const bf16x8*>(
            sm + 32768 + ((size_t)cb * 256 + kh * 128 + (k0 ^ ((cb & 7) << 3))) * 2);
      }
#pragma unroll
      for (int i = 0; i < 2; ++i)
#pragma unroll
        for (int jj = 0; jj < 4; ++jj)
          acc[i][jj] = __builtin_amdgcn_mfma_f32_16x16x32_bf16(a[i], b[jj], acc[i][jj], 0, 0, 0);
    }
  }
  const int g = lane >> 4;
#pragma unroll
  for (int i = 0; i < 2; ++i)
#pragma unroll
    for (int q = 0; q < 4; ++q) {
      int row = row0 + rbase + i * 16 + g * 4 + q;
#pragma unroll
      for (int jj = 0; jj < 4; ++jj)
        h2[(size_t)row * OUT_DIM + jj * 16 + fr] = acc[i][jj][q];
    }
}

// === layer-2 aggregation: wave per dst, single pass, writes d_out ===
__global__ __launch_bounds__(256) void agg2(
    const int* __restrict__ rp, const int* __restrict__ srcs,
    const float* __restrict__ pe, const float* __restrict__ h2,
    const float* __restrict__ b2, float* __restrict__ out) {
  int d = blockIdx.x * 4 + (threadIdx.x >> 6);
  int lane = threadIdx.x & 63;
  int beg = rp[d], end = rp[d + 1];
  float ssum = 0.f, ssum2 = 0.f, acc = 0.f, acc2 = 0.f;
  int j = beg;
  for (; j + 2 <= end; j += 2) {
    int s0 = srcs[j], s1 = srcs[j + 1];
    float p0 = pe[j], p1 = pe[j + 1];
    float v0 = h2[(size_t)s0 * OUT_DIM + lane];
    float v1 = h2[(size_t)s1 * OUT_DIM + lane];
    acc = fmaf(p0, v0, acc); acc2 = fmaf(p1, v1, acc2);
    ssum += p0; ssum2 += p1;
  }
  if (j < end) {
    int s0 = srcs[j];
    float p0 = pe[j];
    acc = fmaf(p0, h2[(size_t)s0 * OUT_DIM + lane], acc);
    ssum += p0;
  }
  acc += acc2; ssum += ssum2;
  out[(size_t)d * OUT_DIM + lane] = acc / fmaxf(ssum, 1e-30f) + b2[lane];
}

extern "C" void kernel_launch(void* const* d_in, const int* in_sizes, int n_in,
                              void* d_out, int out_size, void* d_ws, size_t ws_size,
                              hipStream_t stream) {
  const float* x     = (const float*)d_in[0];
  const float* W1s   = (const float*)d_in[1];
  const float* W1d   = (const float*)d_in[2];
  const float* A1s   = (const float*)d_in[3];
  const float* A1d   = (const float*)d_in[4];
  const float* b1    = (const float*)d_in[5];
  const float* gamma = (const float*)d_in[6];
  const float* beta  = (const float*)d_in[7];
  const float* rmean = (const float*)d_in[8];
  const float* rvar  = (const float*)d_in[9];
  const float* W2s   = (const float*)d_in[10];
  const float* W2d   = (const float*)d_in[11];
  const float* A2s   = (const float*)d_in[12];
  const float* A2d   = (const float*)d_in[13];
  const float* b2    = (const float*)d_in[14];
  const int* src1    = (const int*)d_in[15];
  const int* dst1    = (const int*)d_in[16];
  const int* src2    = (const int*)d_in[17];
  const int* dst2    = (const int*)d_in[18];
  (void)in_sizes; (void)n_in; (void)out_size; (void)ws_size;

  char* W = (char*)d_ws;
  size_t off = 0;
  auto alloc = [&](size_t bytes) { void* p = W + off; off = (off + bytes + 255) & ~(size_t)255; return p; };
  unsigned short* z    = (unsigned short*)alloc((size_t)HEADS * N2 * IN_DIM * 2);
  unsigned short* w1T  = (unsigned short*)alloc((size_t)HD * IN_DIM * 2);
  unsigned short* w2T  = (unsigned short*)alloc((size_t)OUT_DIM * HD * 2);
  unsigned short* acc1 = (unsigned short*)alloc((size_t)N2 * HD * 2);
  float* h2    = (float*)alloc((size_t)N2 * OUT_DIM * 4);
  float* a1s   = (float*)alloc((size_t)N1 * HEADS * 4);
  float* a1d   = (float*)alloc((size_t)N2 * HEADS * 4);
  float* a2s   = (float*)alloc((size_t)N2 * 4);
  float* a2d   = (float*)alloc((size_t)N3 * 4);
  float4* pexp1 = (float4*)alloc((size_t)E1 * 16);
  float* pexp2 = (float*)alloc((size_t)E2 * 4);
  int* deg1    = (int*)alloc((size_t)N2 * 4);
  int* rank1   = (int*)alloc((size_t)E1 * 4);
  int* rp1     = (int*)alloc((size_t)(N2 + 1) * 4);
  int* srcs1   = (int*)alloc((size_t)E1 * 4);
  int* deg2    = (int*)alloc((size_t)N3 * 4);
  int* rank2   = (int*)alloc((size_t)E2 * 4);
  int* rp2     = (int*)alloc((size_t)(N3 + 1) * 4);
  int* srcs2   = (int*)alloc((size_t)E2 * 4);
  float* wa1s  = (float*)alloc(HEADS * IN_DIM * 4);
  float* wa1d  = (float*)alloc(HEADS * IN_DIM * 4);
  float* wa2s  = (float*)alloc(HD * 4);
  float* wa2d  = (float*)alloc(HD * 4);
  float* bnsc  = (float*)alloc(HD * 4);
  float* bnsh  = (float*)alloc(HD * 4);
  int* bsums1  = (int*)alloc(64 * 4);
  int* bsums2  = (int*)alloc(64 * 4);

  setup_k<<<92, 256, 0, stream>>>(W1s, W1d, A1s, A1d, W2s, W2d, A2s, A2d,
                                  b1, gamma, beta, rmean, rvar,
                                  wa1s, wa1d, wa2s, wa2d, bnsc, bnsh,
                                  deg1, deg2, rp1, rp2, a2s, a2d, w1T, w2T);
  hist12_k<<<E1 / 256 + E2 / 256, 256, 0, stream>>>(dst1, deg1, rank1,
                                                    dst2, deg2, rank2);
  scanA_k<<<80, 256, 0, stream>>>(deg1, rp1 + 1, bsums1, deg2, rp2 + 1, bsums2);
  scanB_k<<<2, 256, 0, stream>>>(bsums1, bsums2);
  scanC_k<<<80, 256, 0, stream>>>(rp1 + 1, bsums1, rp2 + 1, bsums2);

  // ---- layer 1 ----
  conv_scores1<<<N1 / 16, 256, 0, stream>>>(x, wa1s, wa1d, a1s, a1d);
  scatter1p_k<<<E1 / 256, 256, 0, stream>>>(src1, dst1, rp1, rank1, a1s, a1d,
                                            srcs1, pexp1);
  agg1x<<<N2 / 4, 256, 0, stream>>>(rp1, srcs1, pexp1, x, z);
  finalize1<<<dim3(N2 / 128, HEADS), 256, 0, stream>>>(
      z, w1T, bnsc, bnsh, wa2s, wa2d, acc1, a2s, a2d);

  // ---- layer 2 ----
  scatter2p_k<<<E2 / 256, 256, 0, stream>>>(src2, dst2, rp2, rank2, a2s, a2d,
                                            srcs2, pexp2);
  gemm2<<<N2 / 128, 256, 0, stream>>>(acc1, w2T, h2);
  agg2<<<N3 / 4, 256, 0, stream>>>(rp2, srcs2, pexp2, h2, b2, (float*)d_out);
}